// Round 8
// baseline (96.857 us; speedup 1.0000x reference)
//
#include <hip/hip_runtime.h>
#include <hip/hip_bf16.h>

// Problem constants (from reference)
#define BB   16
#define NS   1024
#define NT   4096
#define CIN  256
#define CSK  64
#define HD   256           // hidden dim / output cols
#define K1   (CIN + CSK)   // 320
#define MTOT (BB * NT)     // 65536

typedef __attribute__((ext_vector_type(4))) float f32x4;
typedef __attribute__((ext_vector_type(8))) __bf16 bf16x8;
typedef __attribute__((ext_vector_type(4))) unsigned short ushort4v;

// ws layout (bytes)
#define IDX_OFF 0u                    // int[MTOT*3]      = 786432
#define WGT_OFF 786432u               // float[MTOT*3]    = 786432
#define W1F_OFF 1572864u              // bf16[320*256]    = 163840
#define W2F_OFF 1736704u              // bf16[256*256]    = 131072
#define H1_OFF  2097152u              // bf16[MTOT*256]   = 33554432

static __device__ __forceinline__ unsigned short f2bf(float f) {
    union { float f; unsigned int u; } v; v.f = f;
    unsigned int r = (v.u + 0x7FFFu + ((v.u >> 16) & 1u)) >> 16;
    return (unsigned short)r;
}

// async global->LDS, 16 B per lane; dest = wave-uniform base (+ lane*16 by HW)
static __device__ __forceinline__ void gll16(const unsigned short* g, unsigned short* l) {
    __builtin_amdgcn_global_load_lds(
        (const __attribute__((address_space(1))) unsigned int*)g,
        (__attribute__((address_space(3))) unsigned int*)l,
        16, 0, 0);
}

// ---------------- kNN (K=3) over per-cloud 1024 points ----------------
// 16 lanes per query. Exact lex key packed in an integer-valued DOUBLE:
//   key = (double)f32bits(d) * 1024 + s    (< 2^41, exact in f64)
// monotone in d (d >= 0), ties -> lowest s (matches lax.top_k).
#define KNN_P   16
#define KNN_QPB (256 / KNN_P)     // 16 queries per block
__global__ __launch_bounds__(256) void knn_kernel(
    const float* __restrict__ pos, const float* __restrict__ pos_skip,
    int* __restrict__ idx_out, float* __restrict__ wgt_out)
{
    __shared__ float4 sp[NS];
    const int blocks_per_cloud = NT / KNN_QPB;          // 256
    const int cloud = blockIdx.x / blocks_per_cloud;
    const int q = cloud * NT + (blockIdx.x % blocks_per_cloud) * KNN_QPB
                + (threadIdx.x / KNN_P);
    const int p = threadIdx.x & (KNN_P - 1);
    const float* pc = pos + (size_t)cloud * NS * 3;
    for (int i = threadIdx.x; i < NS; i += 256) {
        sp[i] = make_float4(pc[i * 3 + 0], pc[i * 3 + 1], pc[i * 3 + 2], 0.f);
    }
    __syncthreads();

    const float qx = pos_skip[q * 3 + 0];
    const float qy = pos_skip[q * 3 + 1];
    const float qz = pos_skip[q * 3 + 2];

    double b0 = 1e300, b1 = 1e300, b2 = 1e300;
    double si = (double)p;
    #pragma unroll 4
    for (int i = 0; i < NS / KNN_P; ++i) {
        const int s = i * KNN_P + p;
        float4 c = sp[s];
        float dx = qx - c.x, dy = qy - c.y, dz = qz - c.z;
        float d = dx * dx + dy * dy + dz * dz;
        double key = fma((double)__float_as_uint(d), 1024.0, si);
        si += (double)KNN_P;
        double t0 = fmin(b0, key), m0 = fmax(b0, key); b0 = t0;
        double t1 = fmin(b1, m0),  m1 = fmax(b1, m0);  b1 = t1;
        b2 = fmin(b2, m1);
    }
    #pragma unroll
    for (int m = 1; m < KNN_P; m <<= 1) {
        double o0 = __shfl_xor(b0, m, 64);
        double o1 = __shfl_xor(b1, m, 64);
        double o2 = __shfl_xor(b2, m, 64);
        double t0, m0, t1, m1;
        t0 = fmin(b0, o0); m0 = fmax(b0, o0); b0 = t0;
        t1 = fmin(b1, m0); m1 = fmax(b1, m0); b1 = t1;
        b2 = fmin(b2, m1);
        t0 = fmin(b0, o1); m0 = fmax(b0, o1); b0 = t0;
        t1 = fmin(b1, m0); m1 = fmax(b1, m0); b1 = t1;
        b2 = fmin(b2, m1);
        t0 = fmin(b0, o2); m0 = fmax(b0, o2); b0 = t0;
        t1 = fmin(b1, m0); m1 = fmax(b1, m0); b1 = t1;
        b2 = fmin(b2, m1);
    }
    if (p == 0) {
        unsigned long long k0 = (unsigned long long)b0;
        unsigned long long k1 = (unsigned long long)b1;
        unsigned long long k2 = (unsigned long long)b2;
        const int s0 = (int)(k0 & 1023ull);
        const int s1 = (int)(k1 & 1023ull);
        const int s2 = (int)(k2 & 1023ull);
        float d0 = __uint_as_float((unsigned int)(k0 >> 10));
        float d1 = __uint_as_float((unsigned int)(k1 >> 10));
        float d2 = __uint_as_float((unsigned int)(k2 >> 10));
        float w0 = 1.f / fmaxf(d0, 1e-16f);
        float w1 = 1.f / fmaxf(d1, 1e-16f);
        float w2 = 1.f / fmaxf(d2, 1e-16f);
        float inv = 1.f / (w0 + w1 + w2);
        idx_out[q * 3 + 0] = cloud * NS + s0;
        idx_out[q * 3 + 1] = cloud * NS + s1;
        idx_out[q * 3 + 2] = cloud * NS + s2;
        wgt_out[q * 3 + 0] = w0 * inv;
        wgt_out[q * 3 + 1] = w1 * inv;
        wgt_out[q * 3 + 2] = w2 * inv;
    }
}

// ---- prep: W1/W2 swizzle into MFMA B-fragment order + out tail section ----
// Wf layout: Wf[kblk][n(16)][lane(64)][8]
//   k = kblk*32 + (lane>>4)*8 + j ; col = n*16 + (lane&15)
#define PREP_B1 (K1 * HD / 256)         // 320 blocks for W1f
#define PREP_B2 (HD * HD / 256)         // 256 blocks for W2f
#define PREP_B3 ((MTOT * 3) / 256)      // 768 blocks for tail
__global__ __launch_bounds__(256) void prep_kernel(
    const float* __restrict__ W1, const float* __restrict__ W2,
    const float* __restrict__ pos_skip,
    unsigned short* __restrict__ W1f, unsigned short* __restrict__ W2f,
    float* __restrict__ out)
{
    const int b = blockIdx.x;
    if (b < PREP_B1 + PREP_B2) {
        const bool is1 = b < PREP_B1;
        const int id = (is1 ? b : b - PREP_B1) * 256 + threadIdx.x;
        const int j    = id & 7;
        const int lane = (id >> 3) & 63;
        const int n    = (id >> 9) & 15;
        const int kblk = id >> 13;
        const int k   = kblk * 32 + (lane >> 4) * 8 + j;
        const int col = n * 16 + (lane & 15);
        if (is1) W1f[id] = f2bf(W1[(size_t)k * HD + col]);
        else     W2f[id] = f2bf(W2[(size_t)k * HD + col]);
    } else {
        const int i = (b - PREP_B1 - PREP_B2) * 256 + threadIdx.x;
        const size_t o1 = (size_t)MTOT * HD;
        out[o1 + i] = pos_skip[i];                                  // i < MTOT*3
        if (i < MTOT) out[o1 + (size_t)MTOT * 3 + i] = (float)(i >> 12);
    }
}

// ------- fused GEMM1: h1 = relu([interp(x) | x_skip] @ W1 + b1), bf16 out -------
// Block tile 64M x 256N, 4 waves each 64M x 64N.
// ONE-SHOT A staging: wave w stages rows w*16..w*16+15 (mf = w). Per row, all
// 64 lanes do 3 coalesced 1KB row loads + blend, write LDS in MFMA fragment
// order [kb][mf][slot][8] with kb-XOR swizzle (H ^= (kb&7)<<3) so the frag
// reads (lane-consecutive 16B, same uniform XOR) stay conflict-free while the
// writes spread across banks. K-loop then only dbuf-stages B via gll16.
__global__ __launch_bounds__(256, 2) void gemm1_fused_kernel(
    const float* __restrict__ x, const float* __restrict__ x_skip,
    const int* __restrict__ idx, const float* __restrict__ wgt,
    const unsigned short* __restrict__ Wf, const float* __restrict__ bias,
    unsigned short* __restrict__ outb)
{
    constexpr int NKB = K1 / 32;        // 10
    __shared__ __align__(16) unsigned short ldsB[2][16 * 512]; // 32 KB
    __shared__ __align__(16) unsigned short ldsA[NKB * 4 * 512]; // 40 KB, one-shot

    const int tid = threadIdx.x;
    const int w = tid >> 6, lane = tid & 63;
    const int l15 = lane & 15, lk = lane >> 4;

    // cloud<->XCD affinity (bijective on [0,1024))
    const int bid   = blockIdx.x;
    const int xcd   = bid & 7;
    const int j     = bid >> 3;                 // 0..127
    const int cloud = xcd + 8 * (j >> 6);       // 0..15
    const int bm    = cloud * 64 + (j & 63);    // 64-row block index

    // ---- one-shot A staging ----
    {
        const int kbm = lane >> 3;              // main: c=4*lane -> kb
        const int lkm = (lane >> 1) & 3;
        const int em  = lane & 1;
        const int kbs = 8 + (lane >> 5);        // skip: c=256+lane -> kb
        const int lks = (lane >> 3) & 3;
        const int jjs = lane & 7;
        #pragma unroll 8
        for (int r16 = 0; r16 < 16; ++r16) {
            const int row = w * 16 + r16;
            const int rg  = bm * 64 + row;
            const int i0 = idx[rg * 3 + 0], i1 = idx[rg * 3 + 1], i2 = idx[rg * 3 + 2];
            const float w0 = wgt[rg * 3 + 0], w1 = wgt[rg * 3 + 1], w2 = wgt[rg * 3 + 2];
            f32x4 a = *(const f32x4*)(x + (size_t)i0 * CIN + lane * 4);
            f32x4 b = *(const f32x4*)(x + (size_t)i1 * CIN + lane * 4);
            f32x4 c = *(const f32x4*)(x + (size_t)i2 * CIN + lane * 4);
            float s = x_skip[(size_t)rg * CSK + lane];
            f32x4 r = a * w0 + b * w1 + c * w2;
            int H = ((kbm * 4 + w) * 64 + (r16 + 16 * lkm)) * 8 + 4 * em;
            H ^= (kbm & 7) << 3;
            ushort4v o4 = { f2bf(r[0]), f2bf(r[1]), f2bf(r[2]), f2bf(r[3]) };
            *(ushort4v*)&ldsA[H] = o4;
            int H2 = ((kbs * 4 + w) * 64 + (r16 + 16 * lks)) * 8 + jjs;
            H2 ^= (kbs & 7) << 3;
            ldsA[H2] = f2bf(s);
        }
    }

    // ---- B staging helpers (wave w stages n-frags 4w..4w+3) ----
    const unsigned short* wsrc = Wf + w * 2048 + lane * 8;
    unsigned short* ldB0 = &ldsB[0][w * 2048];
    unsigned short* ldB1 = &ldsB[1][w * 2048];
    auto stageB = [&](int kb, unsigned short* d) {
        const unsigned short* s = wsrc + (size_t)kb * 8192;
        gll16(s,        d);
        gll16(s + 512,  d + 512);
        gll16(s + 1024, d + 1024);
        gll16(s + 1536, d + 1536);
    };
    stageB(0, ldB0);

    f32x4 acc[4][4];
    #pragma unroll
    for (int mf = 0; mf < 4; ++mf)
        #pragma unroll
        for (int nf = 0; nf < 4; ++nf)
            acc[mf][nf] = f32x4{0.f, 0.f, 0.f, 0.f};

    for (int kb = 0; kb < NKB; ++kb) {
        __syncthreads();   // A writes + staged B buf[kb&1] visible; prior reads done
        if (kb + 1 < NKB) stageB(kb + 1, (kb & 1) ? ldB0 : ldB1);
        bf16x8 a[4], b[4];
        #pragma unroll
        for (int mf = 0; mf < 4; ++mf) {
            int aoff = ((kb * 4 + mf) * 64 + lane) * 8;
            aoff ^= (kb & 7) << 3;
            a[mf] = *(const bf16x8*)&ldsA[aoff];
        }
        #pragma unroll
        for (int nf = 0; nf < 4; ++nf)
            b[nf] = *(const bf16x8*)&ldsB[kb & 1][(w * 4 + nf) * 512 + lane * 8];
        #pragma unroll
        for (int mf = 0; mf < 4; ++mf)
            #pragma unroll
            for (int nf = 0; nf < 4; ++nf)
                acc[mf][nf] = __builtin_amdgcn_mfma_f32_16x16x32_bf16(
                    a[mf], b[nf], acc[mf][nf], 0, 0, 0);
    }

    // epilogue: col = lane&15 (+16*nf), row = lk*4 + r (+16*mf)
    const int rbase = bm * 64 + lk * 4;
    const int cbase = w * 64 + l15;
    #pragma unroll
    for (int nf = 0; nf < 4; ++nf) {
        const int col = cbase + nf * 16;
        const float bv = bias[col];
        #pragma unroll
        for (int mf = 0; mf < 4; ++mf) {
            #pragma unroll
            for (int r = 0; r < 4; ++r) {
                float v = fmaxf(acc[mf][nf][r] + bv, 0.f);
                outb[(size_t)(rbase + mf * 16 + r) * HD + col] = f2bf(v);
            }
        }
    }
}

// ---------------- GEMM2: out[M,256] = relu(h1[M,256] @ W2 + b2), f32 ----------------
// Block tile 128M x 128N, 4 waves at 64x64 each. XCD-cloud affinity so h1
// reads hit the same XCD L2 that gemm1 wrote.
__global__ __launch_bounds__(256, 3) void gemm2_kernel(
    const unsigned short* __restrict__ A, const unsigned short* __restrict__ Wf,
    const float* __restrict__ bias, float* __restrict__ outf)
{
    constexpr int NKB = HD / 32;        // 8
    __shared__ __align__(16) unsigned short ldsB[2][8 * 512];

    const int tid = threadIdx.x;
    const int w = tid >> 6, lane = tid & 63;
    const int wm = w >> 1, wn = w & 1;
    const int l15 = lane & 15, lk = lane >> 4;

    // cloud<->XCD affinity (bijective on [0,1024)): 64 blocks per cloud
    const int bid   = blockIdx.x;
    const int xcd   = bid & 7;
    const int jj    = bid >> 3;                 // 0..127
    const int cloud = xcd + 8 * (jj >> 6);      // 0..15
    const int q     = jj & 63;
    const int bm    = cloud * 32 + (q >> 1);    // 128-row block index
    const int bn    = q & 1;

    const unsigned short* wsrc = Wf + bn * 4096 + w * 1024 + lane * 8;
    unsigned short* ld0 = &ldsB[0][w * 1024];
    unsigned short* ld1 = &ldsB[1][w * 1024];

    gll16(wsrc,       ld0);
    gll16(wsrc + 512, ld0 + 512);

    const unsigned short* arow = A + (size_t)(bm * 128 + wm * 64 + l15) * HD + lk * 8;

    f32x4 acc[4][4];
    #pragma unroll
    for (int mf = 0; mf < 4; ++mf)
        #pragma unroll
        for (int nf = 0; nf < 4; ++nf)
            acc[mf][nf] = f32x4{0.f, 0.f, 0.f, 0.f};

    for (int kb = 0; kb < NKB; ++kb) {
        __syncthreads();
        if (kb + 1 < NKB) {
            const unsigned short* s = wsrc + (size_t)(kb + 1) * 8192;
            unsigned short* d = (kb & 1) ? ld0 : ld1;
            gll16(s,       d);
            gll16(s + 512, d + 512);
        }
        bf16x8 a[4], b[4];
        #pragma unroll
        for (int mf = 0; mf < 4; ++mf)
            a[mf] = *(const bf16x8*)(arow + (size_t)mf * 16 * HD + kb * 32);
        #pragma unroll
        for (int nf = 0; nf < 4; ++nf)
            b[nf] = *(const bf16x8*)(&ldsB[kb & 1][(wn * 4 + nf) * 512 + lane * 8]);
        #pragma unroll
        for (int mf = 0; mf < 4; ++mf)
            #pragma unroll
            for (int nf = 0; nf < 4; ++nf)
                acc[mf][nf] = __builtin_amdgcn_mfma_f32_16x16x32_bf16(
                    a[mf], b[nf], acc[mf][nf], 0, 0, 0);
    }

    const int rbase = bm * 128 + wm * 64 + lk * 4;
    const int cbase = bn * 128 + wn * 64 + l15;
    #pragma unroll
    for (int nf = 0; nf < 4; ++nf) {
        const int col = cbase + nf * 16;
        const float bv = bias[col];
        #pragma unroll
        for (int mf = 0; mf < 4; ++mf) {
            #pragma unroll
            for (int r = 0; r < 4; ++r) {
                float v = fmaxf(acc[mf][nf][r] + bv, 0.f);
                outf[(size_t)(rbase + mf * 16 + r) * HD + col] = v;
            }
        }
    }
}

extern "C" void kernel_launch(void* const* d_in, const int* in_sizes, int n_in,
                              void* d_out, int out_size, void* d_ws, size_t ws_size,
                              hipStream_t stream)
{
    const float* x        = (const float*)d_in[0];
    const float* pos      = (const float*)d_in[1];
    const float* x_skip   = (const float*)d_in[2];
    const float* pos_skip = (const float*)d_in[3];
    const float* W1       = (const float*)d_in[4];
    const float* b1       = (const float*)d_in[5];
    const float* W2       = (const float*)d_in[6];
    const float* b2       = (const float*)d_in[7];
    float* out = (float*)d_out;

    char* ws = (char*)d_ws;
    int*            idxb = (int*)(ws + IDX_OFF);
    float*          wgtb = (float*)(ws + WGT_OFF);
    unsigned short* W1f  = (unsigned short*)(ws + W1F_OFF);
    unsigned short* W2f  = (unsigned short*)(ws + W2F_OFF);
    unsigned short* h1   = (unsigned short*)(ws + H1_OFF);

    knn_kernel<<<BB * (NT / KNN_QPB), 256, 0, stream>>>(pos, pos_skip, idxb, wgtb);
    prep_kernel<<<PREP_B1 + PREP_B2 + PREP_B3, 256, 0, stream>>>(
        W1, W2, pos_skip, W1f, W2f, out);
    gemm1_fused_kernel<<<MTOT / 64, 256, 0, stream>>>(
        x, x_skip, idxb, wgtb, W1f, b1, h1);
    gemm2_kernel<<<(MTOT / 128) * 2, 256, 0, stream>>>(h1, W2f, b2, out);
}

// Round 9
// 92.891 us; speedup vs baseline: 1.0427x; 1.0427x over previous
//
#include <hip/hip_runtime.h>
#include <hip/hip_bf16.h>

// Problem constants (from reference)
#define BB   16
#define NS   1024
#define NT   4096
#define CIN  256
#define CSK  64
#define HD   256           // hidden dim / output cols
#define K1   (CIN + CSK)   // 320
#define MTOT (BB * NT)     // 65536

typedef __attribute__((ext_vector_type(4))) float f32x4;
typedef __attribute__((ext_vector_type(8))) __bf16 bf16x8;
typedef __attribute__((ext_vector_type(4))) unsigned short ushort4v;

// ws layout (bytes)
#define W1F_OFF 0u                    // bf16[320*256]    = 163840
#define W2F_OFF 163840u               // bf16[256*256]    = 131072
#define H1_OFF  294912u               // bf16[MTOT*256]   = 33554432

static __device__ __forceinline__ unsigned short f2bf(float f) {
    union { float f; unsigned int u; } v; v.f = f;
    unsigned int r = (v.u + 0x7FFFu + ((v.u >> 16) & 1u)) >> 16;
    return (unsigned short)r;
}

// async global->LDS, 16 B per lane; dest = wave-uniform base (+ lane*16 by HW)
static __device__ __forceinline__ void gll16(const unsigned short* g, unsigned short* l) {
    __builtin_amdgcn_global_load_lds(
        (const __attribute__((address_space(1))) unsigned int*)g,
        (__attribute__((address_space(3))) unsigned int*)l,
        16, 0, 0);
}

// ---- prep: W1/W2 swizzle into MFMA B-fragment order + out tail section ----
// Wf layout: Wf[kblk][n(16)][lane(64)][8]
//   k = kblk*32 + (lane>>4)*8 + j ; col = n*16 + (lane&15)
#define PREP_B1 (K1 * HD / 256)         // 320 blocks for W1f
#define PREP_B2 (HD * HD / 256)         // 256 blocks for W2f
#define PREP_B3 ((MTOT * 3) / 256)      // 768 blocks for tail
__global__ __launch_bounds__(256) void prep_kernel(
    const float* __restrict__ W1, const float* __restrict__ W2,
    const float* __restrict__ pos_skip,
    unsigned short* __restrict__ W1f, unsigned short* __restrict__ W2f,
    float* __restrict__ out)
{
    const int b = blockIdx.x;
    if (b < PREP_B1 + PREP_B2) {
        const bool is1 = b < PREP_B1;
        const int id = (is1 ? b : b - PREP_B1) * 256 + threadIdx.x;
        const int j    = id & 7;
        const int lane = (id >> 3) & 63;
        const int n    = (id >> 9) & 15;
        const int kblk = id >> 13;
        const int k   = kblk * 32 + (lane >> 4) * 8 + j;
        const int col = n * 16 + (lane & 15);
        if (is1) W1f[id] = f2bf(W1[(size_t)k * HD + col]);
        else     W2f[id] = f2bf(W2[(size_t)k * HD + col]);
    } else {
        const int i = (b - PREP_B1 - PREP_B2) * 256 + threadIdx.x;
        const size_t o1 = (size_t)MTOT * HD;
        out[o1 + i] = pos_skip[i];                                  // i < MTOT*3
        if (i < MTOT) out[o1 + (size_t)MTOT * 3 + i] = (float)(i >> 12);
    }
}

// ===== FUSED: kNN(64 queries) + interpolate-gather + GEMM1, one block =====
// Block = 64 output rows of one cloud. Phase 1: in-block kNN (P=4 lanes/query,
// exact f64 lex key, identical selection math to the passing standalone knn).
// Phase 2: one-shot A gather/blend into MFMA-fragment LDS (r8-proven code,
// idx/wgt from LDS). Phase 3: B-dbuf k-loop (proven). sp[] overlays ldsA.
__global__ __launch_bounds__(256, 2) void fp_fused_kernel(
    const float* __restrict__ x, const float* __restrict__ x_skip,
    const float* __restrict__ pos, const float* __restrict__ pos_skip,
    const unsigned short* __restrict__ Wf, const float* __restrict__ bias,
    unsigned short* __restrict__ outb)
{
    constexpr int NKB = K1 / 32;        // 10
    __shared__ __align__(16) unsigned short ldsA[NKB * 4 * 512]; // 40 KB (sp overlays)
    __shared__ __align__(16) unsigned short ldsB[2][16 * 512];   // 32 KB
    __shared__ int   sidx[64 * 3];
    __shared__ float swgt[64 * 3];

    const int tid = threadIdx.x;
    const int w = tid >> 6, lane = tid & 63;
    const int l15 = lane & 15, lk = lane >> 4;

    // cloud<->XCD affinity (bijective on [0,1024))
    const int bid   = blockIdx.x;
    const int xcd   = bid & 7;
    const int j     = bid >> 3;                 // 0..127
    const int cloud = xcd + 8 * (j >> 6);       // 0..15
    const int bm    = cloud * 64 + (j & 63);    // 64-row block index

    // ---------------- phase 1: kNN for this block's 64 queries ----------------
    {
        float4* sp = (float4*)ldsA;             // 16 KB overlay, dead after phase 1
        const float* pc = pos + (size_t)cloud * NS * 3;
        for (int i = tid; i < NS; i += 256)
            sp[i] = make_float4(pc[i * 3 + 0], pc[i * 3 + 1], pc[i * 3 + 2], 0.f);
        __syncthreads();

        const int qloc = tid >> 2;              // 0..63
        const int p    = tid & 3;
        const int rg   = bm * 64 + qloc;
        const float qx = pos_skip[rg * 3 + 0];
        const float qy = pos_skip[rg * 3 + 1];
        const float qz = pos_skip[rg * 3 + 2];

        double b0 = 1e300, b1 = 1e300, b2 = 1e300;
        double si = (double)p;
        #pragma unroll 4
        for (int i = 0; i < NS / 4; ++i) {
            const int s = i * 4 + p;
            float4 c = sp[s];
            float dx = qx - c.x, dy = qy - c.y, dz = qz - c.z;
            float d = dx * dx + dy * dy + dz * dz;
            double key = fma((double)__float_as_uint(d), 1024.0, si);
            si += 4.0;
            double t0 = fmin(b0, key), m0 = fmax(b0, key); b0 = t0;
            double t1 = fmin(b1, m0),  m1 = fmax(b1, m0);  b1 = t1;
            b2 = fmin(b2, m1);
        }
        #pragma unroll
        for (int m = 1; m <= 2; m <<= 1) {
            double o0 = __shfl_xor(b0, m, 64);
            double o1 = __shfl_xor(b1, m, 64);
            double o2 = __shfl_xor(b2, m, 64);
            double t0, m0, t1, m1;
            t0 = fmin(b0, o0); m0 = fmax(b0, o0); b0 = t0;
            t1 = fmin(b1, m0); m1 = fmax(b1, m0); b1 = t1;
            b2 = fmin(b2, m1);
            t0 = fmin(b0, o1); m0 = fmax(b0, o1); b0 = t0;
            t1 = fmin(b1, m0); m1 = fmax(b1, m0); b1 = t1;
            b2 = fmin(b2, m1);
            t0 = fmin(b0, o2); m0 = fmax(b0, o2); b0 = t0;
            t1 = fmin(b1, m0); m1 = fmax(b1, m0); b1 = t1;
            b2 = fmin(b2, m1);
        }
        if (p == 0) {
            unsigned long long k0 = (unsigned long long)b0;
            unsigned long long k1 = (unsigned long long)b1;
            unsigned long long k2 = (unsigned long long)b2;
            float d0 = __uint_as_float((unsigned int)(k0 >> 10));
            float d1 = __uint_as_float((unsigned int)(k1 >> 10));
            float d2 = __uint_as_float((unsigned int)(k2 >> 10));
            float w0 = 1.f / fmaxf(d0, 1e-16f);
            float w1 = 1.f / fmaxf(d1, 1e-16f);
            float w2 = 1.f / fmaxf(d2, 1e-16f);
            float inv = 1.f / (w0 + w1 + w2);
            sidx[qloc * 3 + 0] = (int)(k0 & 1023ull);
            sidx[qloc * 3 + 1] = (int)(k1 & 1023ull);
            sidx[qloc * 3 + 2] = (int)(k2 & 1023ull);
            swgt[qloc * 3 + 0] = w0 * inv;
            swgt[qloc * 3 + 1] = w1 * inv;
            swgt[qloc * 3 + 2] = w2 * inv;
        }
        __syncthreads();   // sp reads + sidx/swgt writes complete
    }

    // ---------------- phase 2: one-shot A gather/blend (r8-proven) ----------------
    {
        const int cb  = cloud * NS;             // cloud base row in x
        const int kbm = lane >> 3;              // main: c=4*lane -> kb
        const int lkm = (lane >> 1) & 3;
        const int em  = lane & 1;
        const int kbs = 8 + (lane >> 5);        // skip: c=256+lane -> kb
        const int lks = (lane >> 3) & 3;
        const int jjs = lane & 7;
        #pragma unroll 8
        for (int r16 = 0; r16 < 16; ++r16) {
            const int row = w * 16 + r16;
            const int rg  = bm * 64 + row;
            const int i0 = cb + sidx[row * 3 + 0];
            const int i1 = cb + sidx[row * 3 + 1];
            const int i2 = cb + sidx[row * 3 + 2];
            const float w0 = swgt[row * 3 + 0], w1 = swgt[row * 3 + 1], w2 = swgt[row * 3 + 2];
            f32x4 a = *(const f32x4*)(x + (size_t)i0 * CIN + lane * 4);
            f32x4 b = *(const f32x4*)(x + (size_t)i1 * CIN + lane * 4);
            f32x4 c = *(const f32x4*)(x + (size_t)i2 * CIN + lane * 4);
            float s = x_skip[(size_t)rg * CSK + lane];
            f32x4 r = a * w0 + b * w1 + c * w2;
            int H = ((kbm * 4 + w) * 64 + (r16 + 16 * lkm)) * 8 + 4 * em;
            H ^= (kbm & 7) << 3;
            ushort4v o4 = { f2bf(r[0]), f2bf(r[1]), f2bf(r[2]), f2bf(r[3]) };
            *(ushort4v*)&ldsA[H] = o4;
            int H2 = ((kbs * 4 + w) * 64 + (r16 + 16 * lks)) * 8 + jjs;
            H2 ^= (kbs & 7) << 3;
            ldsA[H2] = f2bf(s);
        }
    }

    // ---------------- phase 3: B-dbuf k-loop (proven) ----------------
    const unsigned short* wsrc = Wf + w * 2048 + lane * 8;
    unsigned short* ldB0 = &ldsB[0][w * 2048];
    unsigned short* ldB1 = &ldsB[1][w * 2048];
    auto stageB = [&](int kb, unsigned short* d) {
        const unsigned short* s = wsrc + (size_t)kb * 8192;
        gll16(s,        d);
        gll16(s + 512,  d + 512);
        gll16(s + 1024, d + 1024);
        gll16(s + 1536, d + 1536);
    };
    stageB(0, ldB0);

    f32x4 acc[4][4];
    #pragma unroll
    for (int mf = 0; mf < 4; ++mf)
        #pragma unroll
        for (int nf = 0; nf < 4; ++nf)
            acc[mf][nf] = f32x4{0.f, 0.f, 0.f, 0.f};

    for (int kb = 0; kb < NKB; ++kb) {
        __syncthreads();   // A writes + staged B buf[kb&1] visible; prior reads done
        if (kb + 1 < NKB) stageB(kb + 1, (kb & 1) ? ldB0 : ldB1);
        bf16x8 a[4], b[4];
        #pragma unroll
        for (int mf = 0; mf < 4; ++mf) {
            int aoff = ((kb * 4 + mf) * 64 + lane) * 8;
            aoff ^= (kb & 7) << 3;
            a[mf] = *(const bf16x8*)&ldsA[aoff];
        }
        #pragma unroll
        for (int nf = 0; nf < 4; ++nf)
            b[nf] = *(const bf16x8*)&ldsB[kb & 1][(w * 4 + nf) * 512 + lane * 8];
        #pragma unroll
        for (int mf = 0; mf < 4; ++mf)
            #pragma unroll
            for (int nf = 0; nf < 4; ++nf)
                acc[mf][nf] = __builtin_amdgcn_mfma_f32_16x16x32_bf16(
                    a[mf], b[nf], acc[mf][nf], 0, 0, 0);
    }

    // epilogue: col = lane&15 (+16*nf), row = lk*4 + r (+16*mf)
    const int rbase = bm * 64 + lk * 4;
    const int cbase = w * 64 + l15;
    #pragma unroll
    for (int nf = 0; nf < 4; ++nf) {
        const int col = cbase + nf * 16;
        const float bv = bias[col];
        #pragma unroll
        for (int mf = 0; mf < 4; ++mf) {
            #pragma unroll
            for (int r = 0; r < 4; ++r) {
                float v = fmaxf(acc[mf][nf][r] + bv, 0.f);
                outb[(size_t)(rbase + mf * 16 + r) * HD + col] = f2bf(v);
            }
        }
    }
}

// ---------------- GEMM2: out[M,256] = relu(h1[M,256] @ W2 + b2), f32 ----------------
// Block tile 128M x 128N, 4 waves at 64x64 each. XCD-cloud affinity so h1
// reads hit the same XCD L2 that the fused kernel wrote.
__global__ __launch_bounds__(256, 3) void gemm2_kernel(
    const unsigned short* __restrict__ A, const unsigned short* __restrict__ Wf,
    const float* __restrict__ bias, float* __restrict__ outf)
{
    constexpr int NKB = HD / 32;        // 8
    __shared__ __align__(16) unsigned short ldsB[2][8 * 512];

    const int tid = threadIdx.x;
    const int w = tid >> 6, lane = tid & 63;
    const int wm = w >> 1, wn = w & 1;
    const int l15 = lane & 15, lk = lane >> 4;

    // cloud<->XCD affinity (bijective on [0,1024)): 64 blocks per cloud
    const int bid   = blockIdx.x;
    const int xcd   = bid & 7;
    const int jj    = bid >> 3;                 // 0..127
    const int cloud = xcd + 8 * (jj >> 6);      // 0..15
    const int q     = jj & 63;
    const int bm    = cloud * 32 + (q >> 1);    // 128-row block index
    const int bn    = q & 1;

    const unsigned short* wsrc = Wf + bn * 4096 + w * 1024 + lane * 8;
    unsigned short* ld0 = &ldsB[0][w * 1024];
    unsigned short* ld1 = &ldsB[1][w * 1024];

    gll16(wsrc,       ld0);
    gll16(wsrc + 512, ld0 + 512);

    const unsigned short* arow = A + (size_t)(bm * 128 + wm * 64 + l15) * HD + lk * 8;

    f32x4 acc[4][4];
    #pragma unroll
    for (int mf = 0; mf < 4; ++mf)
        #pragma unroll
        for (int nf = 0; nf < 4; ++nf)
            acc[mf][nf] = f32x4{0.f, 0.f, 0.f, 0.f};

    for (int kb = 0; kb < NKB; ++kb) {
        __syncthreads();
        if (kb + 1 < NKB) {
            const unsigned short* s = wsrc + (size_t)(kb + 1) * 8192;
            unsigned short* d = (kb & 1) ? ld0 : ld1;
            gll16(s,       d);
            gll16(s + 512, d + 512);
        }
        bf16x8 a[4], b[4];
        #pragma unroll
        for (int mf = 0; mf < 4; ++mf)
            a[mf] = *(const bf16x8*)(arow + (size_t)mf * 16 * HD + kb * 32);
        #pragma unroll
        for (int nf = 0; nf < 4; ++nf)
            b[nf] = *(const bf16x8*)(&ldsB[kb & 1][(wn * 4 + nf) * 512 + lane * 8]);
        #pragma unroll
        for (int mf = 0; mf < 4; ++mf)
            #pragma unroll
            for (int nf = 0; nf < 4; ++nf)
                acc[mf][nf] = __builtin_amdgcn_mfma_f32_16x16x32_bf16(
                    a[mf], b[nf], acc[mf][nf], 0, 0, 0);
    }

    const int rbase = bm * 128 + wm * 64 + lk * 4;
    const int cbase = bn * 128 + wn * 64 + l15;
    #pragma unroll
    for (int nf = 0; nf < 4; ++nf) {
        const int col = cbase + nf * 16;
        const float bv = bias[col];
        #pragma unroll
        for (int mf = 0; mf < 4; ++mf) {
            #pragma unroll
            for (int r = 0; r < 4; ++r) {
                float v = fmaxf(acc[mf][nf][r] + bv, 0.f);
                outf[(size_t)(rbase + mf * 16 + r) * HD + col] = v;
            }
        }
    }
}

extern "C" void kernel_launch(void* const* d_in, const int* in_sizes, int n_in,
                              void* d_out, int out_size, void* d_ws, size_t ws_size,
                              hipStream_t stream)
{
    const float* x        = (const float*)d_in[0];
    const float* pos      = (const float*)d_in[1];
    const float* x_skip   = (const float*)d_in[2];
    const float* pos_skip = (const float*)d_in[3];
    const float* W1       = (const float*)d_in[4];
    const float* b1       = (const float*)d_in[5];
    const float* W2       = (const float*)d_in[6];
    const float* b2       = (const float*)d_in[7];
    float* out = (float*)d_out;

    char* ws = (char*)d_ws;
    unsigned short* W1f  = (unsigned short*)(ws + W1F_OFF);
    unsigned short* W2f  = (unsigned short*)(ws + W2F_OFF);
    unsigned short* h1   = (unsigned short*)(ws + H1_OFF);

    prep_kernel<<<PREP_B1 + PREP_B2 + PREP_B3, 256, 0, stream>>>(
        W1, W2, pos_skip, W1f, W2f, out);
    fp_fused_kernel<<<MTOT / 64, 256, 0, stream>>>(
        x, x_skip, pos, pos_skip, W1f, b1, h1);
    gemm2_kernel<<<(MTOT / 128) * 2, 256, 0, stream>>>(h1, W2f, b2, out);
}

// Round 10
// 92.291 us; speedup vs baseline: 1.0495x; 1.0065x over previous
//
#include <hip/hip_runtime.h>
#include <hip/hip_bf16.h>

// Problem constants (from reference)
#define BB   16
#define NS   1024
#define NT   4096
#define CIN  256
#define CSK  64
#define HD   256           // hidden dim / output cols
#define K1   (CIN + CSK)   // 320
#define MTOT (BB * NT)     // 65536

typedef __attribute__((ext_vector_type(4))) float f32x4;
typedef __attribute__((ext_vector_type(8))) __bf16 bf16x8;
typedef __attribute__((ext_vector_type(4))) unsigned short ushort4v;
typedef __attribute__((ext_vector_type(8))) unsigned short ushort8v;

// ws layout (bytes)
#define W1F_OFF 0u                    // bf16[320*256]    = 163840
#define W2F_OFF 163840u               // bf16[256*256]    = 131072
#define H1_OFF  294912u               // bf16[MTOT*256]   = 33554432

static __device__ __forceinline__ unsigned short f2bf(float f) {
    union { float f; unsigned int u; } v; v.f = f;
    unsigned int r = (v.u + 0x7FFFu + ((v.u >> 16) & 1u)) >> 16;
    return (unsigned short)r;
}

// async global->LDS, 16 B per lane; dest = wave-uniform base (+ lane*16 by HW)
static __device__ __forceinline__ void gll16(const unsigned short* g, unsigned short* l) {
    __builtin_amdgcn_global_load_lds(
        (const __attribute__((address_space(1))) unsigned int*)g,
        (__attribute__((address_space(3))) unsigned int*)l,
        16, 0, 0);
}

// ---- prep: W1/W2 swizzle into MFMA B-fragment order + out tail section ----
// Wf layout: Wf[kblk][n(16)][lane(64)][8]
//   k = kblk*32 + (lane>>4)*8 + j ; col = n*16 + (lane&15)
#define PREP_B1 (K1 * HD / 256)         // 320 blocks for W1f
#define PREP_B2 (HD * HD / 256)         // 256 blocks for W2f
#define PREP_B3 ((MTOT * 3) / 256)      // 768 blocks for tail
__global__ __launch_bounds__(256) void prep_kernel(
    const float* __restrict__ W1, const float* __restrict__ W2,
    const float* __restrict__ pos_skip,
    unsigned short* __restrict__ W1f, unsigned short* __restrict__ W2f,
    float* __restrict__ out)
{
    const int b = blockIdx.x;
    if (b < PREP_B1 + PREP_B2) {
        const bool is1 = b < PREP_B1;
        const int id = (is1 ? b : b - PREP_B1) * 256 + threadIdx.x;
        const int j    = id & 7;
        const int lane = (id >> 3) & 63;
        const int n    = (id >> 9) & 15;
        const int kblk = id >> 13;
        const int k   = kblk * 32 + (lane >> 4) * 8 + j;
        const int col = n * 16 + (lane & 15);
        if (is1) W1f[id] = f2bf(W1[(size_t)k * HD + col]);
        else     W2f[id] = f2bf(W2[(size_t)k * HD + col]);
    } else {
        const int i = (b - PREP_B1 - PREP_B2) * 256 + threadIdx.x;
        const size_t o1 = (size_t)MTOT * HD;
        out[o1 + i] = pos_skip[i];                                  // i < MTOT*3
        if (i < MTOT) out[o1 + (size_t)MTOT * 3 + i] = (float)(i >> 12);
    }
}

// ===== FUSED: kNN(64 queries) + interpolate-gather + GEMM1, one block =====
// Block = 64 output rows of one cloud. LDS budget 49.5 KB -> 3 blocks/CU:
//   ldsA: 8 kb-blocks (main cols only) = 32 KB; skip cols (kb 8,9) come from
//   global x_skip directly into register fragments (same f2bf -> identical bits).
//   ldsB: single 16 KB buffer, stage->barrier->compute->barrier per k-step.
__global__ __launch_bounds__(256, 3) void fp_fused_kernel(
    const float* __restrict__ x, const float* __restrict__ x_skip,
    const float* __restrict__ pos, const float* __restrict__ pos_skip,
    const unsigned short* __restrict__ Wf, const float* __restrict__ bias,
    unsigned short* __restrict__ outb)
{
    __shared__ __align__(16) unsigned short ldsA[8 * 4 * 512];  // 32 KB (sp overlays)
    __shared__ __align__(16) unsigned short ldsB[16 * 512];     // 16 KB single buf
    __shared__ int   sidx[64 * 3];
    __shared__ float swgt[64 * 3];

    const int tid = threadIdx.x;
    const int w = tid >> 6, lane = tid & 63;
    const int l15 = lane & 15, lk = lane >> 4;

    // cloud<->XCD affinity (bijective on [0,1024))
    const int bid   = blockIdx.x;
    const int xcd   = bid & 7;
    const int j     = bid >> 3;                 // 0..127
    const int cloud = xcd + 8 * (j >> 6);       // 0..15
    const int bm    = cloud * 64 + (j & 63);    // 64-row block index

    // ---------------- phase 1: kNN for this block's 64 queries ----------------
    {
        float4* sp = (float4*)ldsA;             // 16 KB overlay, dead after phase 1
        const float* pc = pos + (size_t)cloud * NS * 3;
        for (int i = tid; i < NS; i += 256)
            sp[i] = make_float4(pc[i * 3 + 0], pc[i * 3 + 1], pc[i * 3 + 2], 0.f);
        __syncthreads();

        const int qloc = tid >> 2;              // 0..63
        const int p    = tid & 3;
        const int rg   = bm * 64 + qloc;
        const float qx = pos_skip[rg * 3 + 0];
        const float qy = pos_skip[rg * 3 + 1];
        const float qz = pos_skip[rg * 3 + 2];

        double b0 = 1e300, b1 = 1e300, b2 = 1e300;
        double si = (double)p;
        #pragma unroll 4
        for (int i = 0; i < NS / 4; ++i) {
            const int s = i * 4 + p;
            float4 c = sp[s];
            float dx = qx - c.x, dy = qy - c.y, dz = qz - c.z;
            float d = dx * dx + dy * dy + dz * dz;
            double key = fma((double)__float_as_uint(d), 1024.0, si);
            si += 4.0;
            // shallow sorted-insert (equivalent to 5-op network, depth 2)
            double nb0 = fmin(b0, key);
            double nb1 = fmax(b0, fmin(b1, key));
            double nb2 = fmax(b1, fmin(b2, key));
            b0 = nb0; b1 = nb1; b2 = nb2;
        }
        #pragma unroll
        for (int m = 1; m <= 2; m <<= 1) {
            double o0 = __shfl_xor(b0, m, 64);
            double o1 = __shfl_xor(b1, m, 64);
            double o2 = __shfl_xor(b2, m, 64);
            double nb0, nb1, nb2;
            nb0 = fmin(b0, o0); nb1 = fmax(b0, fmin(b1, o0)); nb2 = fmax(b1, fmin(b2, o0));
            b0 = nb0; b1 = nb1; b2 = nb2;
            nb0 = fmin(b0, o1); nb1 = fmax(b0, fmin(b1, o1)); nb2 = fmax(b1, fmin(b2, o1));
            b0 = nb0; b1 = nb1; b2 = nb2;
            nb0 = fmin(b0, o2); nb1 = fmax(b0, fmin(b1, o2)); nb2 = fmax(b1, fmin(b2, o2));
            b0 = nb0; b1 = nb1; b2 = nb2;
        }
        if (p == 0) {
            unsigned long long k0 = (unsigned long long)b0;
            unsigned long long k1 = (unsigned long long)b1;
            unsigned long long k2 = (unsigned long long)b2;
            float d0 = __uint_as_float((unsigned int)(k0 >> 10));
            float d1 = __uint_as_float((unsigned int)(k1 >> 10));
            float d2 = __uint_as_float((unsigned int)(k2 >> 10));
            float w0 = 1.f / fmaxf(d0, 1e-16f);
            float w1 = 1.f / fmaxf(d1, 1e-16f);
            float w2 = 1.f / fmaxf(d2, 1e-16f);
            float inv = 1.f / (w0 + w1 + w2);
            sidx[qloc * 3 + 0] = (int)(k0 & 1023ull);
            sidx[qloc * 3 + 1] = (int)(k1 & 1023ull);
            sidx[qloc * 3 + 2] = (int)(k2 & 1023ull);
            swgt[qloc * 3 + 0] = w0 * inv;
            swgt[qloc * 3 + 1] = w1 * inv;
            swgt[qloc * 3 + 2] = w2 * inv;
        }
        __syncthreads();   // sp reads + sidx/swgt writes complete
    }

    // ------- phase 2: one-shot A gather/blend (main 256 cols only) -------
    {
        const int cb  = cloud * NS;             // cloud base row in x
        const int kbm = lane >> 3;              // c=4*lane -> kb  (0..7)
        const int lkm = (lane >> 1) & 3;
        const int em  = lane & 1;
        #pragma unroll 4
        for (int r16 = 0; r16 < 16; ++r16) {
            const int row = w * 16 + r16;
            const int i0 = cb + sidx[row * 3 + 0];
            const int i1 = cb + sidx[row * 3 + 1];
            const int i2 = cb + sidx[row * 3 + 2];
            const float w0 = swgt[row * 3 + 0], w1 = swgt[row * 3 + 1], w2 = swgt[row * 3 + 2];
            f32x4 a = *(const f32x4*)(x + (size_t)i0 * CIN + lane * 4);
            f32x4 b = *(const f32x4*)(x + (size_t)i1 * CIN + lane * 4);
            f32x4 c = *(const f32x4*)(x + (size_t)i2 * CIN + lane * 4);
            f32x4 r = a * w0 + b * w1 + c * w2;
            int H = ((kbm * 4 + w) * 64 + (r16 + 16 * lkm)) * 8 + 4 * em;
            H ^= (kbm & 7) << 3;
            ushort4v o4 = { f2bf(r[0]), f2bf(r[1]), f2bf(r[2]), f2bf(r[3]) };
            *(ushort4v*)&ldsA[H] = o4;
        }
    }

    // ------- skip-col A-fragments (kb 8,9) directly from global -> regs -------
    // a-frag: lane holds row (mf*16 + l15), cols 256 + kk*32 + lk*8 .. +8
    bf16x8 skf[2][4];
    #pragma unroll
    for (int kk = 0; kk < 2; ++kk) {
        #pragma unroll
        for (int mf = 0; mf < 4; ++mf) {
            const float* p = x_skip + (size_t)(bm * 64 + mf * 16 + l15) * CSK
                           + kk * 32 + lk * 8;
            f32x4 lo = *(const f32x4*)p;
            f32x4 hi = *(const f32x4*)(p + 4);
            union { ushort8v u; bf16x8 b; } cv;
            cv.u[0] = f2bf(lo[0]); cv.u[1] = f2bf(lo[1]);
            cv.u[2] = f2bf(lo[2]); cv.u[3] = f2bf(lo[3]);
            cv.u[4] = f2bf(hi[0]); cv.u[5] = f2bf(hi[1]);
            cv.u[6] = f2bf(hi[2]); cv.u[7] = f2bf(hi[3]);
            skf[kk][mf] = cv.b;
        }
    }

    // ---------------- phase 3: single-buffer B k-loop ----------------
    const unsigned short* wsrc = Wf + w * 2048 + lane * 8;
    unsigned short* ldB = &ldsB[w * 2048];
    auto stageB = [&](int kb) {
        const unsigned short* s = wsrc + (size_t)kb * 8192;
        gll16(s,        ldB);
        gll16(s + 512,  ldB + 512);
        gll16(s + 1024, ldB + 1024);
        gll16(s + 1536, ldB + 1536);
    };

    f32x4 acc[4][4];
    #pragma unroll
    for (int mf = 0; mf < 4; ++mf)
        #pragma unroll
        for (int nf = 0; nf < 4; ++nf)
            acc[mf][nf] = f32x4{0.f, 0.f, 0.f, 0.f};

    for (int kb = 0; kb < 10; ++kb) {
        stageB(kb);
        __syncthreads();   // vmcnt drained: B[kb] visible (+A writes on kb=0)
        bf16x8 a[4], b[4];
        #pragma unroll
        for (int mf = 0; mf < 4; ++mf) {
            if (kb < 8) {
                int aoff = ((kb * 4 + mf) * 64 + lane) * 8;
                aoff ^= (kb & 7) << 3;
                a[mf] = *(const bf16x8*)&ldsA[aoff];
            } else {
                a[mf] = skf[kb - 8][mf];
            }
        }
        #pragma unroll
        for (int nf = 0; nf < 4; ++nf)
            b[nf] = *(const bf16x8*)&ldsB[(w * 4 + nf) * 512 + lane * 8];
        #pragma unroll
        for (int mf = 0; mf < 4; ++mf)
            #pragma unroll
            for (int nf = 0; nf < 4; ++nf)
                acc[mf][nf] = __builtin_amdgcn_mfma_f32_16x16x32_bf16(
                    a[mf], b[nf], acc[mf][nf], 0, 0, 0);
        __syncthreads();   // reads done; safe to overwrite ldsB next iter
    }

    // epilogue: col = lane&15 (+16*nf), row = lk*4 + r (+16*mf)
    const int rbase = bm * 64 + lk * 4;
    const int cbase = w * 64 + l15;
    #pragma unroll
    for (int nf = 0; nf < 4; ++nf) {
        const int col = cbase + nf * 16;
        const float bv = bias[col];
        #pragma unroll
        for (int mf = 0; mf < 4; ++mf) {
            #pragma unroll
            for (int r = 0; r < 4; ++r) {
                float v = fmaxf(acc[mf][nf][r] + bv, 0.f);
                outb[(size_t)(rbase + mf * 16 + r) * HD + col] = f2bf(v);
            }
        }
    }
}

// ---------------- GEMM2: out[M,256] = relu(h1[M,256] @ W2 + b2), f32 ----------------
// Block tile 128M x 128N, 4 waves at 64x64 each. XCD-cloud affinity so h1
// reads hit the same XCD L2 that the fused kernel wrote.
__global__ __launch_bounds__(256, 3) void gemm2_kernel(
    const unsigned short* __restrict__ A, const unsigned short* __restrict__ Wf,
    const float* __restrict__ bias, float* __restrict__ outf)
{
    constexpr int NKB = HD / 32;        // 8
    __shared__ __align__(16) unsigned short ldsB[2][8 * 512];

    const int tid = threadIdx.x;
    const int w = tid >> 6, lane = tid & 63;
    const int wm = w >> 1, wn = w & 1;
    const int l15 = lane & 15, lk = lane >> 4;

    // cloud<->XCD affinity (bijective on [0,1024)): 64 blocks per cloud
    const int bid   = blockIdx.x;
    const int xcd   = bid & 7;
    const int jj    = bid >> 3;                 // 0..127
    const int cloud = xcd + 8 * (jj >> 6);      // 0..15
    const int q     = jj & 63;
    const int bm    = cloud * 32 + (q >> 1);    // 128-row block index
    const int bn    = q & 1;

    const unsigned short* wsrc = Wf + bn * 4096 + w * 1024 + lane * 8;
    unsigned short* ld0 = &ldsB[0][w * 1024];
    unsigned short* ld1 = &ldsB[1][w * 1024];

    gll16(wsrc,       ld0);
    gll16(wsrc + 512, ld0 + 512);

    const unsigned short* arow = A + (size_t)(bm * 128 + wm * 64 + l15) * HD + lk * 8;

    f32x4 acc[4][4];
    #pragma unroll
    for (int mf = 0; mf < 4; ++mf)
        #pragma unroll
        for (int nf = 0; nf < 4; ++nf)
            acc[mf][nf] = f32x4{0.f, 0.f, 0.f, 0.f};

    for (int kb = 0; kb < NKB; ++kb) {
        __syncthreads();
        if (kb + 1 < NKB) {
            const unsigned short* s = wsrc + (size_t)(kb + 1) * 8192;
            unsigned short* d = (kb & 1) ? ld0 : ld1;
            gll16(s,       d);
            gll16(s + 512, d + 512);
        }
        bf16x8 a[4], b[4];
        #pragma unroll
        for (int mf = 0; mf < 4; ++mf)
            a[mf] = *(const bf16x8*)(arow + (size_t)mf * 16 * HD + kb * 32);
        #pragma unroll
        for (int nf = 0; nf < 4; ++nf)
            b[nf] = *(const bf16x8*)(&ldsB[kb & 1][(wn * 4 + nf) * 512 + lane * 8]);
        #pragma unroll
        for (int mf = 0; mf < 4; ++mf)
            #pragma unroll
            for (int nf = 0; nf < 4; ++nf)
                acc[mf][nf] = __builtin_amdgcn_mfma_f32_16x16x32_bf16(
                    a[mf], b[nf], acc[mf][nf], 0, 0, 0);
    }

    const int rbase = bm * 128 + wm * 64 + lk * 4;
    const int cbase = bn * 128 + wn * 64 + l15;
    #pragma unroll
    for (int nf = 0; nf < 4; ++nf) {
        const int col = cbase + nf * 16;
        const float bv = bias[col];
        #pragma unroll
        for (int mf = 0; mf < 4; ++mf) {
            #pragma unroll
            for (int r = 0; r < 4; ++r) {
                float v = fmaxf(acc[mf][nf][r] + bv, 0.f);
                outf[(size_t)(rbase + mf * 16 + r) * HD + col] = v;
            }
        }
    }
}

extern "C" void kernel_launch(void* const* d_in, const int* in_sizes, int n_in,
                              void* d_out, int out_size, void* d_ws, size_t ws_size,
                              hipStream_t stream)
{
    const float* x        = (const float*)d_in[0];
    const float* pos      = (const float*)d_in[1];
    const float* x_skip   = (const float*)d_in[2];
    const float* pos_skip = (const float*)d_in[3];
    const float* W1       = (const float*)d_in[4];
    const float* b1       = (const float*)d_in[5];
    const float* W2       = (const float*)d_in[6];
    const float* b2       = (const float*)d_in[7];
    float* out = (float*)d_out;

    char* ws = (char*)d_ws;
    unsigned short* W1f  = (unsigned short*)(ws + W1F_OFF);
    unsigned short* W2f  = (unsigned short*)(ws + W2F_OFF);
    unsigned short* h1   = (unsigned short*)(ws + H1_OFF);

    prep_kernel<<<PREP_B1 + PREP_B2 + PREP_B3, 256, 0, stream>>>(
        W1, W2, pos_skip, W1f, W2f, out);
    fp_fused_kernel<<<MTOT / 64, 256, 0, stream>>>(
        x, x_skip, pos, pos_skip, W1f, b1, h1);
    gemm2_kernel<<<(MTOT / 128) * 2, 256, 0, stream>>>(h1, W2f, b2, out);
}

// Round 11
// 81.161 us; speedup vs baseline: 1.1934x; 1.1371x over previous
//
#include <hip/hip_runtime.h>
#include <hip/hip_bf16.h>

// Problem constants (from reference)
#define BB   16
#define NS   1024
#define NT   4096
#define CIN  256
#define CSK  64
#define HD   256           // hidden dim / output cols
#define K1   (CIN + CSK)   // 320
#define MTOT (BB * NT)     // 65536

typedef __attribute__((ext_vector_type(4))) float f32x4;
typedef __attribute__((ext_vector_type(8))) __bf16 bf16x8;
typedef __attribute__((ext_vector_type(4))) unsigned short ushort4v;
typedef __attribute__((ext_vector_type(8))) unsigned short ushort8v;

// ws layout (bytes)
#define W1F_OFF 0u                    // bf16[320*256]    = 163840
#define W2F_OFF 163840u               // bf16[256*256]    = 131072

static __device__ __forceinline__ unsigned short f2bf(float f) {
    union { float f; unsigned int u; } v; v.f = f;
    unsigned int r = (v.u + 0x7FFFu + ((v.u >> 16) & 1u)) >> 16;
    return (unsigned short)r;
}

// async global->LDS, 16 B per lane; dest = wave-uniform base (+ lane*16 by HW)
static __device__ __forceinline__ void gll16(const unsigned short* g, unsigned short* l) {
    __builtin_amdgcn_global_load_lds(
        (const __attribute__((address_space(1))) unsigned int*)g,
        (__attribute__((address_space(3))) unsigned int*)l,
        16, 0, 0);
}

// ---- prep: W1/W2 swizzle into MFMA B-fragment order + out tail section ----
// Wf layout: Wf[kblk][n(16)][lane(64)][8]
//   k = kblk*32 + (lane>>4)*8 + j ; col = n*16 + (lane&15)
#define PREP_B1 (K1 * HD / 256)         // 320 blocks for W1f
#define PREP_B2 (HD * HD / 256)         // 256 blocks for W2f
#define PREP_B3 ((MTOT * 3) / 256)      // 768 blocks for tail
__global__ __launch_bounds__(256) void prep_kernel(
    const float* __restrict__ W1, const float* __restrict__ W2,
    const float* __restrict__ pos_skip,
    unsigned short* __restrict__ W1f, unsigned short* __restrict__ W2f,
    float* __restrict__ out)
{
    const int b = blockIdx.x;
    if (b < PREP_B1 + PREP_B2) {
        const bool is1 = b < PREP_B1;
        const int id = (is1 ? b : b - PREP_B1) * 256 + threadIdx.x;
        const int j    = id & 7;
        const int lane = (id >> 3) & 63;
        const int n    = (id >> 9) & 15;
        const int kblk = id >> 13;
        const int k   = kblk * 32 + (lane >> 4) * 8 + j;
        const int col = n * 16 + (lane & 15);
        if (is1) W1f[id] = f2bf(W1[(size_t)k * HD + col]);
        else     W2f[id] = f2bf(W2[(size_t)k * HD + col]);
    } else {
        const int i = (b - PREP_B1 - PREP_B2) * 256 + threadIdx.x;
        const size_t o1 = (size_t)MTOT * HD;
        out[o1 + i] = pos_skip[i];                                  // i < MTOT*3
        if (i < MTOT) out[o1 + (size_t)MTOT * 3 + i] = (float)(i >> 12);
    }
}

// ===== MEGAKERNEL: kNN + interp-gather + GEMM1 + GEMM2 per 64-row block =====
// LDS 49.5 KB -> 3 blocks/CU. ldsA (32 KB): sp overlay -> gemm1 A-tile (main
// 256 cols) -> h1 tile in A-frag layout for gemm2. ldsB (16 KB): single-buffer
// W1f/W2f staging. Skip cols (kb 8,9) live in register fragments.
__global__ __launch_bounds__(256, 3) void fp_fused_kernel(
    const float* __restrict__ x, const float* __restrict__ x_skip,
    const float* __restrict__ pos, const float* __restrict__ pos_skip,
    const unsigned short* __restrict__ W1f, const unsigned short* __restrict__ W2f,
    const float* __restrict__ b1, const float* __restrict__ b2,
    float* __restrict__ out)
{
    __shared__ __align__(16) unsigned short ldsA[8 * 4 * 512];  // 32 KB
    __shared__ __align__(16) unsigned short ldsB[16 * 512];     // 16 KB
    __shared__ int   sidx[64 * 3];
    __shared__ float swgt[64 * 3];

    const int tid = threadIdx.x;
    const int w = tid >> 6, lane = tid & 63;
    const int l15 = lane & 15, lk = lane >> 4;

    // cloud<->XCD affinity (bijective on [0,1024))
    const int bid   = blockIdx.x;
    const int xcd   = bid & 7;
    const int j     = bid >> 3;                 // 0..127
    const int cloud = xcd + 8 * (j >> 6);       // 0..15
    const int bm    = cloud * 64 + (j & 63);    // 64-row block index

    // B staging (wave w stages n-frags 4w..4w+3 of the current kb-block)
    unsigned short* ldB = &ldsB[w * 2048];
    const unsigned short* w1src = W1f + w * 2048 + lane * 8;
    const unsigned short* w2src = W2f + w * 2048 + lane * 8;
    auto stageB = [&](const unsigned short* src, int kb) {
        const unsigned short* s = src + (size_t)kb * 8192;
        gll16(s,        ldB);
        gll16(s + 512,  ldB + 512);
        gll16(s + 1024, ldB + 1024);
        gll16(s + 1536, ldB + 1536);
    };
    stageB(w1src, 0);   // hide first B fill under the kNN phase

    // ---------------- phase 1: kNN for this block's 64 queries ----------------
    {
        float4* sp = (float4*)ldsA;             // 16 KB overlay, dead after phase 1
        const float* pc = pos + (size_t)cloud * NS * 3;
        for (int i = tid; i < NS; i += 256)
            sp[i] = make_float4(pc[i * 3 + 0], pc[i * 3 + 1], pc[i * 3 + 2], 0.f);
        __syncthreads();

        const int qloc = tid >> 2;              // 0..63
        const int p    = tid & 3;
        const int rg   = bm * 64 + qloc;
        const float qx = pos_skip[rg * 3 + 0];
        const float qy = pos_skip[rg * 3 + 1];
        const float qz = pos_skip[rg * 3 + 2];

        double b0 = 1e300, b1k = 1e300, b2k = 1e300;
        double si = (double)p;
        #pragma unroll 4
        for (int i = 0; i < NS / 4; ++i) {
            const int s = i * 4 + p;
            float4 c = sp[s];
            float dx = qx - c.x, dy = qy - c.y, dz = qz - c.z;
            float d = dx * dx + dy * dy + dz * dz;
            double key = fma((double)__float_as_uint(d), 1024.0, si);
            si += 4.0;
            double nb0 = fmin(b0, key);
            double nb1 = fmax(b0, fmin(b1k, key));
            double nb2 = fmax(b1k, fmin(b2k, key));
            b0 = nb0; b1k = nb1; b2k = nb2;
        }
        #pragma unroll
        for (int m = 1; m <= 2; m <<= 1) {
            double o0 = __shfl_xor(b0, m, 64);
            double o1 = __shfl_xor(b1k, m, 64);
            double o2 = __shfl_xor(b2k, m, 64);
            double nb0, nb1, nb2;
            nb0 = fmin(b0, o0); nb1 = fmax(b0, fmin(b1k, o0)); nb2 = fmax(b1k, fmin(b2k, o0));
            b0 = nb0; b1k = nb1; b2k = nb2;
            nb0 = fmin(b0, o1); nb1 = fmax(b0, fmin(b1k, o1)); nb2 = fmax(b1k, fmin(b2k, o1));
            b0 = nb0; b1k = nb1; b2k = nb2;
            nb0 = fmin(b0, o2); nb1 = fmax(b0, fmin(b1k, o2)); nb2 = fmax(b1k, fmin(b2k, o2));
            b0 = nb0; b1k = nb1; b2k = nb2;
        }
        if (p == 0) {
            unsigned long long k0 = (unsigned long long)b0;
            unsigned long long k1 = (unsigned long long)b1k;
            unsigned long long k2 = (unsigned long long)b2k;
            float d0 = __uint_as_float((unsigned int)(k0 >> 10));
            float d1 = __uint_as_float((unsigned int)(k1 >> 10));
            float d2 = __uint_as_float((unsigned int)(k2 >> 10));
            float w0 = 1.f / fmaxf(d0, 1e-16f);
            float w1 = 1.f / fmaxf(d1, 1e-16f);
            float w2 = 1.f / fmaxf(d2, 1e-16f);
            float inv = 1.f / (w0 + w1 + w2);
            sidx[qloc * 3 + 0] = (int)(k0 & 1023ull);
            sidx[qloc * 3 + 1] = (int)(k1 & 1023ull);
            sidx[qloc * 3 + 2] = (int)(k2 & 1023ull);
            swgt[qloc * 3 + 0] = w0 * inv;
            swgt[qloc * 3 + 1] = w1 * inv;
            swgt[qloc * 3 + 2] = w2 * inv;
        }
        __syncthreads();   // sp reads + sidx/swgt writes complete
    }

    // ------- phase 2: one-shot A gather/blend (main 256 cols only) -------
    {
        const int cb  = cloud * NS;             // cloud base row in x
        const int kbm = lane >> 3;              // c=4*lane -> kb  (0..7)
        const int lkm = (lane >> 1) & 3;
        const int em  = lane & 1;
        #pragma unroll 4
        for (int r16 = 0; r16 < 16; ++r16) {
            const int row = w * 16 + r16;
            const int i0 = cb + sidx[row * 3 + 0];
            const int i1 = cb + sidx[row * 3 + 1];
            const int i2 = cb + sidx[row * 3 + 2];
            const float w0 = swgt[row * 3 + 0], w1 = swgt[row * 3 + 1], w2 = swgt[row * 3 + 2];
            f32x4 a = *(const f32x4*)(x + (size_t)i0 * CIN + lane * 4);
            f32x4 b = *(const f32x4*)(x + (size_t)i1 * CIN + lane * 4);
            f32x4 c = *(const f32x4*)(x + (size_t)i2 * CIN + lane * 4);
            f32x4 r = a * w0 + b * w1 + c * w2;
            int H = ((kbm * 4 + w) * 64 + (r16 + 16 * lkm)) * 8 + 4 * em;
            H ^= (kbm & 7) << 3;
            ushort4v o4 = { f2bf(r[0]), f2bf(r[1]), f2bf(r[2]), f2bf(r[3]) };
            *(ushort4v*)&ldsA[H] = o4;
        }
    }

    // ------- skip-col A-fragments (kb 8,9) directly from global -> regs -------
    bf16x8 skf[2][4];
    #pragma unroll
    for (int kk = 0; kk < 2; ++kk) {
        #pragma unroll
        for (int mf = 0; mf < 4; ++mf) {
            const float* p = x_skip + (size_t)(bm * 64 + mf * 16 + l15) * CSK
                           + kk * 32 + lk * 8;
            f32x4 lo = *(const f32x4*)p;
            f32x4 hi = *(const f32x4*)(p + 4);
            union { ushort8v u; bf16x8 b; } cv;
            cv.u[0] = f2bf(lo[0]); cv.u[1] = f2bf(lo[1]);
            cv.u[2] = f2bf(lo[2]); cv.u[3] = f2bf(lo[3]);
            cv.u[4] = f2bf(hi[0]); cv.u[5] = f2bf(hi[1]);
            cv.u[6] = f2bf(hi[2]); cv.u[7] = f2bf(hi[3]);
            skf[kk][mf] = cv.b;
        }
    }

    // ---------------- phase 3: GEMM1 k-loop (single-buffer B) ----------------
    f32x4 acc[4][4];
    #pragma unroll
    for (int mf = 0; mf < 4; ++mf)
        #pragma unroll
        for (int nf = 0; nf < 4; ++nf)
            acc[mf][nf] = f32x4{0.f, 0.f, 0.f, 0.f};

    for (int kb = 0; kb < 10; ++kb) {
        __syncthreads();   // B[kb] staged+drained (+A/LDS writes on kb=0)
        bf16x8 a[4], b[4];
        #pragma unroll
        for (int mf = 0; mf < 4; ++mf) {
            if (kb < 8) {
                int aoff = ((kb * 4 + mf) * 64 + lane) * 8;
                aoff ^= (kb & 7) << 3;
                a[mf] = *(const bf16x8*)&ldsA[aoff];
            } else {
                a[mf] = skf[kb - 8][mf];
            }
        }
        #pragma unroll
        for (int nf = 0; nf < 4; ++nf)
            b[nf] = *(const bf16x8*)&ldsB[(w * 4 + nf) * 512 + lane * 8];
        #pragma unroll
        for (int mf = 0; mf < 4; ++mf)
            #pragma unroll
            for (int nf = 0; nf < 4; ++nf)
                acc[mf][nf] = __builtin_amdgcn_mfma_f32_16x16x32_bf16(
                    a[mf], b[nf], acc[mf][nf], 0, 0, 0);
        __syncthreads();   // reads of ldsB (and last ldsA at kb=7) done
        if (kb + 1 < 10)      stageB(w1src, kb + 1);
        else                  stageB(w2src, 0);           // prefetch gemm2 B
    }

    // ------- phase 4: h1 = relu(acc + b1) -> bf16 -> ldsA in A-frag layout -------
    // elem (row=mf*16+lk*4+r, col=w*64+nf*16+l15):
    //   kb2 = 2w + (nf>>1); lane2 = lk*4+r + 16*((nf&1)*2 + (l15>>3)); j = l15&7
    #pragma unroll
    for (int nf = 0; nf < 4; ++nf) {
        const int col = w * 64 + nf * 16 + l15;
        const float bv = b1[col];
        const int kb2   = 2 * w + (nf >> 1);
        const int lane2 = lk * 4 + 16 * ((nf & 1) * 2 + (l15 >> 3));
        #pragma unroll
        for (int mf = 0; mf < 4; ++mf) {
            #pragma unroll
            for (int r = 0; r < 4; ++r) {
                float v = fmaxf(acc[mf][nf][r] + bv, 0.f);
                ldsA[((kb2 * 4 + mf) * 64 + lane2 + r) * 8 + (l15 & 7)] = f2bf(v);
            }
        }
    }

    // ---------------- phase 5: GEMM2 k-loop (single-buffer B) ----------------
    f32x4 acc2[4][4];
    #pragma unroll
    for (int mf = 0; mf < 4; ++mf)
        #pragma unroll
        for (int nf = 0; nf < 4; ++nf)
            acc2[mf][nf] = f32x4{0.f, 0.f, 0.f, 0.f};

    for (int kb = 0; kb < 8; ++kb) {
        __syncthreads();   // B2[kb] staged+drained (+h1 LDS writes on kb=0)
        bf16x8 a[4], b[4];
        #pragma unroll
        for (int mf = 0; mf < 4; ++mf)
            a[mf] = *(const bf16x8*)&ldsA[((kb * 4 + mf) * 64 + lane) * 8];
        #pragma unroll
        for (int nf = 0; nf < 4; ++nf)
            b[nf] = *(const bf16x8*)&ldsB[(w * 4 + nf) * 512 + lane * 8];
        #pragma unroll
        for (int mf = 0; mf < 4; ++mf)
            #pragma unroll
            for (int nf = 0; nf < 4; ++nf)
                acc2[mf][nf] = __builtin_amdgcn_mfma_f32_16x16x32_bf16(
                    a[mf], b[nf], acc2[mf][nf], 0, 0, 0);
        __syncthreads();
        if (kb + 1 < 8) stageB(w2src, kb + 1);
    }

    // epilogue: out = relu(acc2 + b2), f32
    const int rbase = bm * 64 + lk * 4;
    const int cbase = w * 64 + l15;
    #pragma unroll
    for (int nf = 0; nf < 4; ++nf) {
        const int col = cbase + nf * 16;
        const float bv = b2[col];
        #pragma unroll
        for (int mf = 0; mf < 4; ++mf) {
            #pragma unroll
            for (int r = 0; r < 4; ++r) {
                float v = fmaxf(acc2[mf][nf][r] + bv, 0.f);
                out[(size_t)(rbase + mf * 16 + r) * HD + col] = v;
            }
        }
    }
}

extern "C" void kernel_launch(void* const* d_in, const int* in_sizes, int n_in,
                              void* d_out, int out_size, void* d_ws, size_t ws_size,
                              hipStream_t stream)
{
    const float* x        = (const float*)d_in[0];
    const float* pos      = (const float*)d_in[1];
    const float* x_skip   = (const float*)d_in[2];
    const float* pos_skip = (const float*)d_in[3];
    const float* W1       = (const float*)d_in[4];
    const float* b1       = (const float*)d_in[5];
    const float* W2       = (const float*)d_in[6];
    const float* b2       = (const float*)d_in[7];
    float* out = (float*)d_out;

    char* ws = (char*)d_ws;
    unsigned short* W1f  = (unsigned short*)(ws + W1F_OFF);
    unsigned short* W2f  = (unsigned short*)(ws + W2F_OFF);

    prep_kernel<<<PREP_B1 + PREP_B2 + PREP_B3, 256, 0, stream>>>(
        W1, W2, pos_skip, W1f, W2f, out);
    fp_fused_kernel<<<MTOT / 64, 256, 0, stream>>>(
        x, x_skip, pos, pos_skip, W1f, W2f, b1, b2, out);
}

// Round 12
// 63.424 us; speedup vs baseline: 1.5271x; 1.2797x over previous
//
#include <hip/hip_runtime.h>
#include <hip/hip_bf16.h>

// Problem constants (from reference)
#define BB   16
#define NS   1024
#define NT   4096
#define CIN  256
#define CSK  64
#define HD   256           // hidden dim / output cols
#define K1   (CIN + CSK)   // 320
#define MTOT (BB * NT)     // 65536

typedef __attribute__((ext_vector_type(4))) float f32x4;
typedef __attribute__((ext_vector_type(8))) __bf16 bf16x8;
typedef __attribute__((ext_vector_type(4))) unsigned short ushort4v;

// ws layout (bytes)
#define W1F_OFF 0u                    // bf16[320*256]    = 163840
#define W2F_OFF 163840u               // bf16[256*256]    = 131072

static __device__ __forceinline__ unsigned short f2bf(float f) {
    union { float f; unsigned int u; } v; v.f = f;
    unsigned int r = (v.u + 0x7FFFu + ((v.u >> 16) & 1u)) >> 16;
    return (unsigned short)r;
}
// HW bf16 convert (v_cvt_pk_bf16_f32, RNE — bit-identical to f2bf on finite)
static __device__ __forceinline__ unsigned short f2bf_hw(float f) {
    union { __bf16 b; unsigned short u; } v; v.b = (__bf16)f;
    return v.u;
}

// ---- prep: W1/W2 swizzle into MFMA B-fragment order + out tail section ----
// Wf layout: Wf[kblk][n(16)][lane(64)][8]
//   k = kblk*32 + (lane>>4)*8 + j ; col = n*16 + (lane&15)
#define PREP_B1 (K1 * HD / 256)         // 320 blocks for W1f
#define PREP_B2 (HD * HD / 256)         // 256 blocks for W2f
#define PREP_B3 ((MTOT * 3) / 256)      // 768 blocks for tail
__global__ __launch_bounds__(256) void prep_kernel(
    const float* __restrict__ W1, const float* __restrict__ W2,
    const float* __restrict__ pos_skip,
    unsigned short* __restrict__ W1f, unsigned short* __restrict__ W2f,
    float* __restrict__ out)
{
    const int b = blockIdx.x;
    if (b < PREP_B1 + PREP_B2) {
        const bool is1 = b < PREP_B1;
        const int id = (is1 ? b : b - PREP_B1) * 256 + threadIdx.x;
        const int j    = id & 7;
        const int lane = (id >> 3) & 63;
        const int n    = (id >> 9) & 15;
        const int kblk = id >> 13;
        const int k   = kblk * 32 + (lane >> 4) * 8 + j;
        const int col = n * 16 + (lane & 15);
        if (is1) W1f[id] = f2bf(W1[(size_t)k * HD + col]);
        else     W2f[id] = f2bf(W2[(size_t)k * HD + col]);
    } else {
        const int i = (b - PREP_B1 - PREP_B2) * 256 + threadIdx.x;
        const size_t o1 = (size_t)MTOT * HD;
        out[o1 + i] = pos_skip[i];                                  // i < MTOT*3
        if (i < MTOT) out[o1 + (size_t)MTOT * 3 + i] = (float)(i >> 12);
    }
}

// ===== MEGAKERNEL: kNN + interp-gather + GEMM1 + GEMM2 per 64-row block =====
// Barrier-minimal design (5 barriers total): B operands stream L2->VGPR
// (no ldsB, no k-loop barriers). ldsA (40 KB) holds the full 320-col A tile
// in MFMA fragment order, then is reused for the h1 tile. 3 blocks/CU.
__global__ __launch_bounds__(256, 3) void fp_fused_kernel(
    const float* __restrict__ x, const float* __restrict__ x_skip,
    const float* __restrict__ pos, const float* __restrict__ pos_skip,
    const unsigned short* __restrict__ W1f, const unsigned short* __restrict__ W2f,
    const float* __restrict__ b1, const float* __restrict__ b2,
    float* __restrict__ out)
{
    __shared__ __align__(16) unsigned short ldsA[10 * 4 * 512]; // 40 KB
    __shared__ int   sidx[64 * 3];
    __shared__ float swgt[64 * 3];

    const int tid = threadIdx.x;
    const int w = tid >> 6, lane = tid & 63;
    const int l15 = lane & 15, lk = lane >> 4;

    // cloud<->XCD affinity (bijective on [0,1024))
    const int bid   = blockIdx.x;
    const int xcd   = bid & 7;
    const int j     = bid >> 3;                 // 0..127
    const int cloud = xcd + 8 * (j >> 6);       // 0..15
    const int bm    = cloud * 64 + (j & 63);    // 64-row block index

    // ---------------- phase 1: kNN for this block's 64 queries ----------------
    {
        float4* sp = (float4*)ldsA;             // 16 KB overlay, dead after phase 1
        const float* pc = pos + (size_t)cloud * NS * 3;
        for (int i = tid; i < NS; i += 256)
            sp[i] = make_float4(pc[i * 3 + 0], pc[i * 3 + 1], pc[i * 3 + 2], 0.f);
        __syncthreads();                                            // [1]

        const int qloc = tid >> 2;              // 0..63
        const int p    = tid & 3;
        const int rg   = bm * 64 + qloc;
        const float qx = pos_skip[rg * 3 + 0];
        const float qy = pos_skip[rg * 3 + 1];
        const float qz = pos_skip[rg * 3 + 2];

        double b0 = 1e300, b1k = 1e300, b2k = 1e300;
        double si = (double)p;
        #pragma unroll 4
        for (int i = 0; i < NS / 4; ++i) {
            const int s = i * 4 + p;
            float4 c = sp[s];
            float dx = qx - c.x, dy = qy - c.y, dz = qz - c.z;
            float d = dx * dx + dy * dy + dz * dz;
            double key = fma((double)__float_as_uint(d), 1024.0, si);
            si += 4.0;
            double nb0 = fmin(b0, key);
            double nb1 = fmax(b0, fmin(b1k, key));
            double nb2 = fmax(b1k, fmin(b2k, key));
            b0 = nb0; b1k = nb1; b2k = nb2;
        }
        #pragma unroll
        for (int m = 1; m <= 2; m <<= 1) {
            double o0 = __shfl_xor(b0, m, 64);
            double o1 = __shfl_xor(b1k, m, 64);
            double o2 = __shfl_xor(b2k, m, 64);
            double nb0, nb1, nb2;
            nb0 = fmin(b0, o0); nb1 = fmax(b0, fmin(b1k, o0)); nb2 = fmax(b1k, fmin(b2k, o0));
            b0 = nb0; b1k = nb1; b2k = nb2;
            nb0 = fmin(b0, o1); nb1 = fmax(b0, fmin(b1k, o1)); nb2 = fmax(b1k, fmin(b2k, o1));
            b0 = nb0; b1k = nb1; b2k = nb2;
            nb0 = fmin(b0, o2); nb1 = fmax(b0, fmin(b1k, o2)); nb2 = fmax(b1k, fmin(b2k, o2));
            b0 = nb0; b1k = nb1; b2k = nb2;
        }
        if (p == 0) {
            unsigned long long k0 = (unsigned long long)b0;
            unsigned long long k1 = (unsigned long long)b1k;
            unsigned long long k2 = (unsigned long long)b2k;
            float d0 = __uint_as_float((unsigned int)(k0 >> 10));
            float d1 = __uint_as_float((unsigned int)(k1 >> 10));
            float d2 = __uint_as_float((unsigned int)(k2 >> 10));
            float w0 = 1.f / fmaxf(d0, 1e-16f);
            float w1 = 1.f / fmaxf(d1, 1e-16f);
            float w2 = 1.f / fmaxf(d2, 1e-16f);
            float inv = 1.f / (w0 + w1 + w2);
            sidx[qloc * 3 + 0] = (int)(k0 & 1023ull);
            sidx[qloc * 3 + 1] = (int)(k1 & 1023ull);
            sidx[qloc * 3 + 2] = (int)(k2 & 1023ull);
            swgt[qloc * 3 + 0] = w0 * inv;
            swgt[qloc * 3 + 1] = w1 * inv;
            swgt[qloc * 3 + 2] = w2 * inv;
        }
        __syncthreads();   // [2] sp reads + sidx/swgt writes complete
    }

    // ------- phase 2: one-shot A gather/blend (all 320 cols -> ldsA) -------
    {
        const int cb  = cloud * NS;             // cloud base row in x
        const int kbm = lane >> 3;              // main: c=4*lane -> kb (0..7)
        const int lkm = (lane >> 1) & 3;
        const int em  = lane & 1;
        const int kbs = 8 + (lane >> 5);        // skip: c=256+lane -> kb (8,9)
        const int lks = (lane >> 3) & 3;
        const int jjs = lane & 7;
        #pragma unroll 4
        for (int r16 = 0; r16 < 16; ++r16) {
            const int row = w * 16 + r16;
            const int rg  = bm * 64 + row;
            const int i0 = cb + sidx[row * 3 + 0];
            const int i1 = cb + sidx[row * 3 + 1];
            const int i2 = cb + sidx[row * 3 + 2];
            const float w0 = swgt[row * 3 + 0], w1 = swgt[row * 3 + 1], w2 = swgt[row * 3 + 2];
            f32x4 a = *(const f32x4*)(x + (size_t)i0 * CIN + lane * 4);
            f32x4 b = *(const f32x4*)(x + (size_t)i1 * CIN + lane * 4);
            f32x4 c = *(const f32x4*)(x + (size_t)i2 * CIN + lane * 4);
            float s = x_skip[(size_t)rg * CSK + lane];
            f32x4 r = a * w0 + b * w1 + c * w2;
            int H = ((kbm * 4 + w) * 64 + (r16 + 16 * lkm)) * 8 + 4 * em;
            H ^= (kbm & 7) << 3;
            ushort4v o4 = { f2bf_hw(r[0]), f2bf_hw(r[1]), f2bf_hw(r[2]), f2bf_hw(r[3]) };
            *(ushort4v*)&ldsA[H] = o4;
            int H2 = ((kbs * 4 + w) * 64 + (r16 + 16 * lks)) * 8 + jjs;
            H2 ^= (kbs & 7) << 3;
            ldsA[H2] = f2bf_hw(s);
        }
    }
    __syncthreads();   // [3] A tile complete

    // ---------------- phase 3: GEMM1 k-loop, barrier-free (B: L2->VGPR) ----------------
    const unsigned short* w1p = W1f + (w * 4) * 512 + lane * 8;
    const unsigned short* w2p = W2f + (w * 4) * 512 + lane * 8;

    f32x4 acc[4][4];
    #pragma unroll
    for (int mf = 0; mf < 4; ++mf)
        #pragma unroll
        for (int nf = 0; nf < 4; ++nf)
            acc[mf][nf] = f32x4{0.f, 0.f, 0.f, 0.f};

    {
        bf16x8 bc[4], bn[4];
        #pragma unroll
        for (int nf = 0; nf < 4; ++nf)
            bc[nf] = *(const bf16x8*)(w1p + nf * 512);
        #pragma unroll
        for (int kb = 0; kb < 10; ++kb) {
            if (kb < 9) {
                #pragma unroll
                for (int nf = 0; nf < 4; ++nf)
                    bn[nf] = *(const bf16x8*)(w1p + (size_t)(kb + 1) * 8192 + nf * 512);
            }
            bf16x8 a[4];
            #pragma unroll
            for (int mf = 0; mf < 4; ++mf) {
                int aoff = ((kb * 4 + mf) * 64 + lane) * 8;
                aoff ^= (kb & 7) << 3;
                a[mf] = *(const bf16x8*)&ldsA[aoff];
            }
            #pragma unroll
            for (int mf = 0; mf < 4; ++mf)
                #pragma unroll
                for (int nf = 0; nf < 4; ++nf)
                    acc[mf][nf] = __builtin_amdgcn_mfma_f32_16x16x32_bf16(
                        a[mf], bc[nf], acc[mf][nf], 0, 0, 0);
            #pragma unroll
            for (int nf = 0; nf < 4; ++nf) bc[nf] = bn[nf];
        }
    }
    __syncthreads();   // [4] all ldsA reads done; safe to overwrite with h1

    // ------- phase 4: h1 = relu(acc + b1) -> bf16 -> ldsA in A-frag layout -------
    // elem (row=mf*16+lk*4+r, col=w*64+nf*16+l15):
    //   kb2 = 2w + (nf>>1); lane2 = lk*4+r + 16*((nf&1)*2 + (l15>>3)); j = l15&7
    #pragma unroll
    for (int nf = 0; nf < 4; ++nf) {
        const int col = w * 64 + nf * 16 + l15;
        const float bv = b1[col];
        const int kb2   = 2 * w + (nf >> 1);
        const int lane2 = lk * 4 + 16 * ((nf & 1) * 2 + (l15 >> 3));
        #pragma unroll
        for (int mf = 0; mf < 4; ++mf) {
            #pragma unroll
            for (int r = 0; r < 4; ++r) {
                float v = fmaxf(acc[mf][nf][r] + bv, 0.f);
                ldsA[((kb2 * 4 + mf) * 64 + lane2 + r) * 8 + (l15 & 7)] = f2bf_hw(v);
            }
        }
    }
    __syncthreads();   // [5] h1 tile complete

    // ---------------- phase 5: GEMM2 k-loop, barrier-free ----------------
    f32x4 acc2[4][4];
    #pragma unroll
    for (int mf = 0; mf < 4; ++mf)
        #pragma unroll
        for (int nf = 0; nf < 4; ++nf)
            acc2[mf][nf] = f32x4{0.f, 0.f, 0.f, 0.f};

    {
        bf16x8 bc[4], bn[4];
        #pragma unroll
        for (int nf = 0; nf < 4; ++nf)
            bc[nf] = *(const bf16x8*)(w2p + nf * 512);
        #pragma unroll
        for (int kb = 0; kb < 8; ++kb) {
            if (kb < 7) {
                #pragma unroll
                for (int nf = 0; nf < 4; ++nf)
                    bn[nf] = *(const bf16x8*)(w2p + (size_t)(kb + 1) * 8192 + nf * 512);
            }
            bf16x8 a[4];
            #pragma unroll
            for (int mf = 0; mf < 4; ++mf)
                a[mf] = *(const bf16x8*)&ldsA[((kb * 4 + mf) * 64 + lane) * 8];
            #pragma unroll
            for (int mf = 0; mf < 4; ++mf)
                #pragma unroll
                for (int nf = 0; nf < 4; ++nf)
                    acc2[mf][nf] = __builtin_amdgcn_mfma_f32_16x16x32_bf16(
                        a[mf], bc[nf], acc2[mf][nf], 0, 0, 0);
            #pragma unroll
            for (int nf = 0; nf < 4; ++nf) bc[nf] = bn[nf];
        }
    }

    // epilogue: out = relu(acc2 + b2), f32
    const int rbase = bm * 64 + lk * 4;
    const int cbase = w * 64 + l15;
    #pragma unroll
    for (int nf = 0; nf < 4; ++nf) {
        const int col = cbase + nf * 16;
        const float bv = b2[col];
        #pragma unroll
        for (int mf = 0; mf < 4; ++mf) {
            #pragma unroll
            for (int r = 0; r < 4; ++r) {
                float v = fmaxf(acc2[mf][nf][r] + bv, 0.f);
                out[(size_t)(rbase + mf * 16 + r) * HD + col] = v;
            }
        }
    }
}

extern "C" void kernel_launch(void* const* d_in, const int* in_sizes, int n_in,
                              void* d_out, int out_size, void* d_ws, size_t ws_size,
                              hipStream_t stream)
{
    const float* x        = (const float*)d_in[0];
    const float* pos      = (const float*)d_in[1];
    const float* x_skip   = (const float*)d_in[2];
    const float* pos_skip = (const float*)d_in[3];
    const float* W1       = (const float*)d_in[4];
    const float* b1       = (const float*)d_in[5];
    const float* W2       = (const float*)d_in[6];
    const float* b2       = (const float*)d_in[7];
    float* out = (float*)d_out;

    char* ws = (char*)d_ws;
    unsigned short* W1f  = (unsigned short*)(ws + W1F_OFF);
    unsigned short* W2f  = (unsigned short*)(ws + W2F_OFF);

    prep_kernel<<<PREP_B1 + PREP_B2 + PREP_B3, 256, 0, stream>>>(
        W1, W2, pos_skip, W1f, W2f, out);
    fp_fused_kernel<<<MTOT / 64, 256, 0, stream>>>(
        x, x_skip, pos, pos_skip, W1f, W2f, b1, b2, out);
}

// Round 13
// 62.939 us; speedup vs baseline: 1.5389x; 1.0077x over previous
//
#include <hip/hip_runtime.h>
#include <hip/hip_bf16.h>

// Problem constants (from reference)
#define BB   16
#define NS   1024
#define NT   4096
#define CIN  256
#define CSK  64
#define HD   256           // hidden dim / output cols
#define K1   (CIN + CSK)   // 320
#define MTOT (BB * NT)     // 65536

typedef __attribute__((ext_vector_type(4))) float f32x4;
typedef __attribute__((ext_vector_type(8))) __bf16 bf16x8;
typedef __attribute__((ext_vector_type(4))) unsigned short ushort4v;

// ws layout (bytes)
#define W1F_OFF 0u                    // bf16[320*256]    = 163840
#define W2F_OFF 163840u               // bf16[256*256]    = 131072

static __device__ __forceinline__ unsigned short f2bf(float f) {
    union { float f; unsigned int u; } v; v.f = f;
    unsigned int r = (v.u + 0x7FFFu + ((v.u >> 16) & 1u)) >> 16;
    return (unsigned short)r;
}
// HW bf16 convert (v_cvt_pk_bf16_f32, RNE — bit-identical to f2bf on finite)
static __device__ __forceinline__ unsigned short f2bf_hw(float f) {
    union { __bf16 b; unsigned short u; } v; v.b = (__bf16)f;
    return v.u;
}

// ---- prep: W1/W2 swizzle into MFMA B-fragment order + out tail section ----
// Wf layout: Wf[kblk][n(16)][lane(64)][8]
//   k = kblk*32 + (lane>>4)*8 + j ; col = n*16 + (lane&15)
#define PREP_B1 (K1 * HD / 256)         // 320 blocks for W1f
#define PREP_B2 (HD * HD / 256)         // 256 blocks for W2f
#define PREP_B3 ((MTOT * 3) / 256)      // 768 blocks for tail
__global__ __launch_bounds__(256) void prep_kernel(
    const float* __restrict__ W1, const float* __restrict__ W2,
    const float* __restrict__ pos_skip,
    unsigned short* __restrict__ W1f, unsigned short* __restrict__ W2f,
    float* __restrict__ out)
{
    const int b = blockIdx.x;
    if (b < PREP_B1 + PREP_B2) {
        const bool is1 = b < PREP_B1;
        const int id = (is1 ? b : b - PREP_B1) * 256 + threadIdx.x;
        const int j    = id & 7;
        const int lane = (id >> 3) & 63;
        const int n    = (id >> 9) & 15;
        const int kblk = id >> 13;
        const int k   = kblk * 32 + (lane >> 4) * 8 + j;
        const int col = n * 16 + (lane & 15);
        if (is1) W1f[id] = f2bf(W1[(size_t)k * HD + col]);
        else     W2f[id] = f2bf(W2[(size_t)k * HD + col]);
    } else {
        const int i = (b - PREP_B1 - PREP_B2) * 256 + threadIdx.x;
        const size_t o1 = (size_t)MTOT * HD;
        out[o1 + i] = pos_skip[i];                                  // i < MTOT*3
        if (i < MTOT) out[o1 + (size_t)MTOT * 3 + i] = (float)(i >> 12);
    }
}

// ===== MEGAKERNEL: kNN + interp-gather + GEMM1 + GEMM2 per 64-row block =====
// Barrier-minimal (5 barriers). B operands stream L2->VGPR (no ldsB).
// ldsA = exactly 40960 B (no sidx/swgt: kNN results broadcast via readlane,
// gather row-bases become SGPR-uniform) -> 4 blocks/CU (4*40960 = 160 KB).
__global__ __launch_bounds__(256, 4) void fp_fused_kernel(
    const float* __restrict__ x, const float* __restrict__ x_skip,
    const float* __restrict__ pos, const float* __restrict__ pos_skip,
    const unsigned short* __restrict__ W1f, const unsigned short* __restrict__ W2f,
    const float* __restrict__ b1, const float* __restrict__ b2,
    float* __restrict__ out)
{
    __shared__ __align__(16) unsigned short ldsA[10 * 4 * 512]; // 40 KB exactly

    const int tid = threadIdx.x;
    const int w = tid >> 6, lane = tid & 63;
    const int l15 = lane & 15, lk = lane >> 4;

    // cloud<->XCD affinity (bijective on [0,1024))
    const int bid   = blockIdx.x;
    const int xcd   = bid & 7;
    const int j     = bid >> 3;                 // 0..127
    const int cloud = xcd + 8 * (j >> 6);       // 0..15
    const int bm    = cloud * 64 + (j & 63);    // 64-row block index

    // ---------------- phase 1: kNN for this block's 64 queries ----------------
    // Query q = tid>>2 (row of this block), partition p = tid&3.
    int   myi0, myi1, myi2;          // per-query results (all 4 lanes of group)
    float myw0, myw1, myw2;
    {
        float4* sp = (float4*)ldsA;             // 16 KB overlay, dead after phase 1
        const float* pc = pos + (size_t)cloud * NS * 3;
        for (int i = tid; i < NS; i += 256)
            sp[i] = make_float4(pc[i * 3 + 0], pc[i * 3 + 1], pc[i * 3 + 2], 0.f);
        __syncthreads();                                            // [1]

        const int p  = tid & 3;
        const int rg = bm * 64 + (tid >> 2);
        const float qx = pos_skip[rg * 3 + 0];
        const float qy = pos_skip[rg * 3 + 1];
        const float qz = pos_skip[rg * 3 + 2];

        double b0 = 1e300, b1k = 1e300, b2k = 1e300;
        double si = (double)p;
        #pragma unroll 4
        for (int i = 0; i < NS / 4; ++i) {
            const int s = i * 4 + p;
            float4 c = sp[s];
            float dx = qx - c.x, dy = qy - c.y, dz = qz - c.z;
            float d = dx * dx + dy * dy + dz * dz;
            double key = fma((double)__float_as_uint(d), 1024.0, si);
            si += 4.0;
            double nb0 = fmin(b0, key);
            double nb1 = fmax(b0, fmin(b1k, key));
            double nb2 = fmax(b1k, fmin(b2k, key));
            b0 = nb0; b1k = nb1; b2k = nb2;
        }
        #pragma unroll
        for (int m = 1; m <= 2; m <<= 1) {
            double o0 = __shfl_xor(b0, m, 64);
            double o1 = __shfl_xor(b1k, m, 64);
            double o2 = __shfl_xor(b2k, m, 64);
            double nb0, nb1, nb2;
            nb0 = fmin(b0, o0); nb1 = fmax(b0, fmin(b1k, o0)); nb2 = fmax(b1k, fmin(b2k, o0));
            b0 = nb0; b1k = nb1; b2k = nb2;
            nb0 = fmin(b0, o1); nb1 = fmax(b0, fmin(b1k, o1)); nb2 = fmax(b1k, fmin(b2k, o1));
            b0 = nb0; b1k = nb1; b2k = nb2;
            nb0 = fmin(b0, o2); nb1 = fmax(b0, fmin(b1k, o2)); nb2 = fmax(b1k, fmin(b2k, o2));
            b0 = nb0; b1k = nb1; b2k = nb2;
        }
        // all 4 lanes of the group hold the merged triple -> decode everywhere
        unsigned long long k0 = (unsigned long long)b0;
        unsigned long long k1 = (unsigned long long)b1k;
        unsigned long long k2 = (unsigned long long)b2k;
        myi0 = (int)(k0 & 1023ull);
        myi1 = (int)(k1 & 1023ull);
        myi2 = (int)(k2 & 1023ull);
        float d0 = __uint_as_float((unsigned int)(k0 >> 10));
        float d1 = __uint_as_float((unsigned int)(k1 >> 10));
        float d2 = __uint_as_float((unsigned int)(k2 >> 10));
        float w0 = 1.f / fmaxf(d0, 1e-16f);
        float w1 = 1.f / fmaxf(d1, 1e-16f);
        float w2 = 1.f / fmaxf(d2, 1e-16f);
        float inv = 1.f / (w0 + w1 + w2);
        myw0 = w0 * inv; myw1 = w1 * inv; myw2 = w2 * inv;
        __syncthreads();   // [2] sp reads complete (ldsA about to be overwritten)
    }

    // ------- phase 2: one-shot A gather/blend (all 320 cols -> ldsA) -------
    // Row w*16+r16's kNN result lives in lane 4*r16 of THIS wave: readlane ->
    // SGPR row-bases, uniform addressing.
    {
        const int cb  = cloud * NS;             // cloud base row in x
        const int kbm = lane >> 3;              // main: c=4*lane -> kb (0..7)
        const int lkm = (lane >> 1) & 3;
        const int em  = lane & 1;
        const int kbs = 8 + (lane >> 5);        // skip: c=256+lane -> kb (8,9)
        const int lks = (lane >> 3) & 3;
        const int jjs = lane & 7;
        #pragma unroll
        for (int r16 = 0; r16 < 16; ++r16) {
            const int src = r16 * 4;
            const int i0 = cb + __shfl(myi0, src, 64);
            const int i1 = cb + __shfl(myi1, src, 64);
            const int i2 = cb + __shfl(myi2, src, 64);
            const float w0 = __shfl(myw0, src, 64);
            const float w1 = __shfl(myw1, src, 64);
            const float w2 = __shfl(myw2, src, 64);
            const int row = w * 16 + r16;
            const int rg  = bm * 64 + row;
            f32x4 a = *(const f32x4*)(x + (size_t)i0 * CIN + lane * 4);
            f32x4 b = *(const f32x4*)(x + (size_t)i1 * CIN + lane * 4);
            f32x4 c = *(const f32x4*)(x + (size_t)i2 * CIN + lane * 4);
            float s = x_skip[(size_t)rg * CSK + lane];
            f32x4 r = a * w0 + b * w1 + c * w2;
            int H = ((kbm * 4 + w) * 64 + (r16 + 16 * lkm)) * 8 + 4 * em;
            H ^= (kbm & 7) << 3;
            ushort4v o4 = { f2bf_hw(r[0]), f2bf_hw(r[1]), f2bf_hw(r[2]), f2bf_hw(r[3]) };
            *(ushort4v*)&ldsA[H] = o4;
            int H2 = ((kbs * 4 + w) * 64 + (r16 + 16 * lks)) * 8 + jjs;
            H2 ^= (kbs & 7) << 3;
            ldsA[H2] = f2bf_hw(s);
        }
    }
    __syncthreads();   // [3] A tile complete

    // ---------------- phase 3: GEMM1 k-loop, barrier-free (B: L2->VGPR) ----------------
    const unsigned short* w1p = W1f + (w * 4) * 512 + lane * 8;
    const unsigned short* w2p = W2f + (w * 4) * 512 + lane * 8;

    f32x4 acc[4][4];
    #pragma unroll
    for (int mf = 0; mf < 4; ++mf)
        #pragma unroll
        for (int nf = 0; nf < 4; ++nf)
            acc[mf][nf] = f32x4{0.f, 0.f, 0.f, 0.f};

    {
        bf16x8 bc[4], bn[4];
        #pragma unroll
        for (int nf = 0; nf < 4; ++nf)
            bc[nf] = *(const bf16x8*)(w1p + nf * 512);
        #pragma unroll
        for (int kb = 0; kb < 10; ++kb) {
            if (kb < 9) {
                #pragma unroll
                for (int nf = 0; nf < 4; ++nf)
                    bn[nf] = *(const bf16x8*)(w1p + (size_t)(kb + 1) * 8192 + nf * 512);
            }
            bf16x8 a[4];
            #pragma unroll
            for (int mf = 0; mf < 4; ++mf) {
                int aoff = ((kb * 4 + mf) * 64 + lane) * 8;
                aoff ^= (kb & 7) << 3;
                a[mf] = *(const bf16x8*)&ldsA[aoff];
            }
            #pragma unroll
            for (int mf = 0; mf < 4; ++mf)
                #pragma unroll
                for (int nf = 0; nf < 4; ++nf)
                    acc[mf][nf] = __builtin_amdgcn_mfma_f32_16x16x32_bf16(
                        a[mf], bc[nf], acc[mf][nf], 0, 0, 0);
            #pragma unroll
            for (int nf = 0; nf < 4; ++nf) bc[nf] = bn[nf];
        }
    }
    __syncthreads();   // [4] all ldsA reads done; safe to overwrite with h1

    // ------- phase 4: h1 = relu(acc + b1) -> bf16 -> ldsA in A-frag layout -------
    // elem (row=mf*16+lk*4+r, col=w*64+nf*16+l15):
    //   kb2 = 2w + (nf>>1); lane2 = lk*4+r + 16*((nf&1)*2 + (l15>>3)); j = l15&7
    #pragma unroll
    for (int nf = 0; nf < 4; ++nf) {
        const int col = w * 64 + nf * 16 + l15;
        const float bv = b1[col];
        const int kb2   = 2 * w + (nf >> 1);
        const int lane2 = lk * 4 + 16 * ((nf & 1) * 2 + (l15 >> 3));
        #pragma unroll
        for (int mf = 0; mf < 4; ++mf) {
            #pragma unroll
            for (int r = 0; r < 4; ++r) {
                float v = fmaxf(acc[mf][nf][r] + bv, 0.f);
                ldsA[((kb2 * 4 + mf) * 64 + lane2 + r) * 8 + (l15 & 7)] = f2bf_hw(v);
            }
        }
    }
    __syncthreads();   // [5] h1 tile complete

    // ---------------- phase 5: GEMM2 k-loop, barrier-free ----------------
    f32x4 acc2[4][4];
    #pragma unroll
    for (int mf = 0; mf < 4; ++mf)
        #pragma unroll
        for (int nf = 0; nf < 4; ++nf)
            acc2[mf][nf] = f32x4{0.f, 0.f, 0.f, 0.f};

    {
        bf16x8 bc[4], bn[4];
        #pragma unroll
        for (int nf = 0; nf < 4; ++nf)
            bc[nf] = *(const bf16x8*)(w2p + nf * 512);
        #pragma unroll
        for (int kb = 0; kb < 8; ++kb) {
            if (kb < 7) {
                #pragma unroll
                for (int nf = 0; nf < 4; ++nf)
                    bn[nf] = *(const bf16x8*)(w2p + (size_t)(kb + 1) * 8192 + nf * 512);
            }
            bf16x8 a[4];
            #pragma unroll
            for (int mf = 0; mf < 4; ++mf)
                a[mf] = *(const bf16x8*)&ldsA[((kb * 4 + mf) * 64 + lane) * 8];
            #pragma unroll
            for (int mf = 0; mf < 4; ++mf)
                #pragma unroll
                for (int nf = 0; nf < 4; ++nf)
                    acc2[mf][nf] = __builtin_amdgcn_mfma_f32_16x16x32_bf16(
                        a[mf], bc[nf], acc2[mf][nf], 0, 0, 0);
            #pragma unroll
            for (int nf = 0; nf < 4; ++nf) bc[nf] = bn[nf];
        }
    }

    // epilogue: out = relu(acc2 + b2), f32
    const int rbase = bm * 64 + lk * 4;
    const int cbase = w * 64 + l15;
    #pragma unroll
    for (int nf = 0; nf < 4; ++nf) {
        const int col = cbase + nf * 16;
        const float bv = b2[col];
        #pragma unroll
        for (int mf = 0; mf < 4; ++mf) {
            #pragma unroll
            for (int r = 0; r < 4; ++r) {
                float v = fmaxf(acc2[mf][nf][r] + bv, 0.f);
                out[(size_t)(rbase + mf * 16 + r) * HD + col] = v;
            }
        }
    }
}

extern "C" void kernel_launch(void* const* d_in, const int* in_sizes, int n_in,
                              void* d_out, int out_size, void* d_ws, size_t ws_size,
                              hipStream_t stream)
{
    const float* x        = (const float*)d_in[0];
    const float* pos      = (const float*)d_in[1];
    const float* x_skip   = (const float*)d_in[2];
    const float* pos_skip = (const float*)d_in[3];
    const float* W1       = (const float*)d_in[4];
    const float* b1       = (const float*)d_in[5];
    const float* W2       = (const float*)d_in[6];
    const float* b2       = (const float*)d_in[7];
    float* out = (float*)d_out;

    char* ws = (char*)d_ws;
    unsigned short* W1f  = (unsigned short*)(ws + W1F_OFF);
    unsigned short* W2f  = (unsigned short*)(ws + W2F_OFF);

    prep_kernel<<<PREP_B1 + PREP_B2 + PREP_B3, 256, 0, stream>>>(
        W1, W2, pos_skip, W1f, W2f, out);
    fp_fused_kernel<<<MTOT / 64, 256, 0, stream>>>(
        x, x_skip, pos, pos_skip, W1f, W2f, b1, b2, out);
}